// Round 12
// baseline (5154.809 us; speedup 1.0000x reference)
//
#include <hip/hip_runtime.h>
#include <stdint.h>

typedef unsigned short ushort_t;
using frag8 = __attribute__((ext_vector_type(8))) short;
using f32x4 = __attribute__((ext_vector_type(4))) float;

static __device__ __forceinline__ unsigned short f2bf(float f) {
  union { float f; unsigned u; } v; v.f = f;
  unsigned r = v.u + 0x7fffu + ((v.u >> 16) & 1u);
  return (unsigned short)(r >> 16);
}
static __device__ __forceinline__ float bf2f(unsigned short b) {
  union { unsigned u; float f; } v; v.u = ((unsigned)b) << 16; return v.f;
}
static __device__ __forceinline__ void splitf(float v, ushort_t& h, ushort_t& m) {
  h = f2bf(v);
  m = f2bf(v - bf2f(h));
}

// ---------------- pix split ----------------
__global__ __launch_bounds__(256) void k_splitpix(const float* __restrict__ pix,
                                                  ushort_t* __restrict__ oh,
                                                  ushort_t* __restrict__ om, int n4) {
  int i = blockIdx.x * 256 + threadIdx.x;
  if (i >= n4) return;
  float4 v = ((const float4*)pix)[i];
  ushort4 h, m;
  splitf(2.f * (v.x - 0.5f), h.x, m.x);
  splitf(2.f * (v.y - 0.5f), h.y, m.y);
  splitf(2.f * (v.z - 0.5f), h.z, m.z);
  splitf(2.f * (v.w - 0.5f), h.w, m.w);
  ((ushort4*)oh)[i] = h;
  ((ushort4*)om)[i] = m;
}

// ---------------- transpose-split: f32 [K][N] -> bf16 hi/mid [N][K] ----------------
__global__ __launch_bounds__(256) void k_wsplit4(const float* __restrict__ B0,
                                                 const float* __restrict__ B1,
                                                 const float* __restrict__ B2,
                                                 const float* __restrict__ B3,
                                                 ushort_t* __restrict__ th,
                                                 ushort_t* __restrict__ tm,
                                                 int K, int N) {
  __shared__ float ts[64][65];
  const int z = blockIdx.z;
  const float* B = (z == 0) ? B0 : (z == 1) ? B1 : (z == 2) ? B2 : B3;
  th += (size_t)z * K * N;
  tm += (size_t)z * K * N;
  const int tid = threadIdx.x;
  const int n0 = blockIdx.x << 6, k0 = blockIdx.y << 6;
  int rr = tid >> 4, cc = (tid & 15) << 2;
#pragma unroll
  for (int j = 0; j < 4; ++j) {
    int r = rr + j * 16;
    float4 v = *(const float4*)(B + (size_t)(k0 + r) * N + n0 + cc);
    ts[r][cc] = v.x; ts[r][cc + 1] = v.y; ts[r][cc + 2] = v.z; ts[r][cc + 3] = v.w;
  }
  __syncthreads();
  int n = tid >> 2;
  int kc = (tid & 3) << 4;
  ushort_t oh[16], om[16];
#pragma unroll
  for (int j = 0; j < 16; ++j) splitf(ts[kc + j][n], oh[j], om[j]);
  ushort_t* ph = th + (size_t)(n0 + n) * K + k0 + kc;
  ushort_t* pm = tm + (size_t)(n0 + n) * K + k0 + kc;
  *(uint4*)(ph) = *(uint4*)(oh);
  *(uint4*)(ph + 8) = *(uint4*)(oh + 8);
  *(uint4*)(pm) = *(uint4*)(om);
  *(uint4*)(pm + 8) = *(uint4*)(om + 8);
}

// ---------------- pos-emb fill ----------------
__global__ __launch_bounds__(256) void k_posemb(const int* __restrict__ pos,
                                                const float* __restrict__ ptab,
                                                float* __restrict__ x) {
  int row = blockIdx.x, tid = threadIdx.x;
  int p0 = pos[(size_t)row * 2], p1 = pos[(size_t)row * 2 + 1];
  bool pad = (p0 == -1) && (p1 == -1);
  int px = p0 > 0 ? p0 : 0, py = p1 > 0 ? p1 : 0;
  float4 a = ((const float4*)(ptab + (size_t)px * 1024))[tid];
  float4 b = ((const float4*)(ptab + 65536 + (size_t)py * 1024))[tid];
  float4 o;
  o.x = pad ? 0.f : a.x + b.x;
  o.y = pad ? 0.f : a.y + b.y;
  o.z = pad ? 0.f : a.z + b.z;
  o.w = pad ? 0.f : a.w + b.w;
  ((float4*)(x + (size_t)row * 1024))[tid] = o;
}

// ---------------- RMSNorm D=1024: f32 -> hi/mid bf16 ----------------
__global__ __launch_bounds__(256) void k_rmsnorm_s(const float* __restrict__ x,
                                                   const float* __restrict__ scale,
                                                   ushort_t* __restrict__ oh,
                                                   ushort_t* __restrict__ om) {
  __shared__ float wsum[4];
  int row = blockIdx.x, tid = threadIdx.x;
  float4 v = ((const float4*)(x + (size_t)row * 1024))[tid];
  float ss = v.x * v.x + v.y * v.y + v.z * v.z + v.w * v.w;
  for (int m = 1; m < 64; m <<= 1) ss += __shfl_xor(ss, m);
  if ((tid & 63) == 0) wsum[tid >> 6] = ss;
  __syncthreads();
  float tot = wsum[0] + wsum[1] + wsum[2] + wsum[3];
  float r = rsqrtf(tot * (1.f / 1024.f) + 1e-6f);
  float4 sc = ((const float4*)scale)[tid];
  ushort4 h, m;
  splitf(v.x * r * sc.x, h.x, m.x);
  splitf(v.y * r * sc.y, h.y, m.y);
  splitf(v.z * r * sc.z, h.z, m.z);
  splitf(v.w * r * sc.w, h.w, m.w);
  ((ushort4*)(oh + (size_t)row * 1024))[tid] = h;
  ((ushort4*)(om + (size_t)row * 1024))[tid] = m;
}

// ---------------- x += RMSNorm(t1+t2)*scale (f32) ----------------
__global__ __launch_bounds__(256) void k_addrms32(float* __restrict__ x,
                                                  const float* __restrict__ t1,
                                                  const float* __restrict__ t2,
                                                  const float* __restrict__ scale) {
  __shared__ float wsum[4];
  int row = blockIdx.x, tid = threadIdx.x;
  float4 v = ((const float4*)(t1 + (size_t)row * 1024))[tid];
  float4 v2 = ((const float4*)(t2 + (size_t)row * 1024))[tid];
  v.x += v2.x; v.y += v2.y; v.z += v2.z; v.w += v2.w;
  float ss = v.x * v.x + v.y * v.y + v.z * v.z + v.w * v.w;
  for (int m = 1; m < 64; m <<= 1) ss += __shfl_xor(ss, m);
  if ((tid & 63) == 0) wsum[tid >> 6] = ss;
  __syncthreads();
  float tot = wsum[0] + wsum[1] + wsum[2] + wsum[3];
  float r = rsqrtf(tot * (1.f / 1024.f) + 1e-6f);
  float4 sc = ((const float4*)scale)[tid];
  float4 xv = ((const float4*)(x + (size_t)row * 1024))[tid];
  xv.x += v.x * r * sc.x;
  xv.y += v.y * r * sc.y;
  xv.z += v.z * r * sc.z;
  xv.w += v.w * r * sc.w;
  ((float4*)(x + (size_t)row * 1024))[tid] = xv;
}

#define SWZ_COL(r, c) (((c) ^ (((r) >> 3) & 3)) << 3)

// ================= fused QKV GEMM + per-head RMS + RoPE (256x128 tile, mi=8) =================
__global__ __launch_bounds__(256, 2) void k_qkv(const ushort_t* __restrict__ Ah,
                                                const ushort_t* __restrict__ Am,
                                                const ushort_t* __restrict__ WT_h,
                                                const ushort_t* __restrict__ WT_m,
                                                const float* __restrict__ qn,
                                                const float* __restrict__ kn,
                                                const int* __restrict__ pos,
                                                ushort_t* __restrict__ qh, ushort_t* __restrict__ qm,
                                                ushort_t* __restrict__ kh, ushort_t* __restrict__ km,
                                                ushort_t* __restrict__ vh, ushort_t* __restrict__ vm) {
  __shared__ __align__(16) ushort_t Ash[256][40];
  __shared__ __align__(16) ushort_t Asl[256][40];
  __shared__ __align__(16) ushort_t Bsh[128][40];
  __shared__ __align__(16) ushort_t Bsl[128][40];
  const int tid = threadIdx.x;
  const int bid = blockIdx.x;              // 384 blocks
  const int xcd = bid & 7, lo = bid >> 3;  // lo 0..47
  const int ntl = lo % 3, mt = lo / 3;     // mt 0..15
  const int nt = xcd * 3 + ntl;            // 0..23
  const int mat = nt >> 3;
  const int n0 = (nt & 7) << 7;
  const int m0 = mt << 8;
  const ushort_t* Bh = WT_h + (size_t)mat * 1048576;
  const ushort_t* Bm = WT_m + (size_t)mat * 1048576;

  const int lane = tid & 63;
  const int wm = ((tid >> 7) & 1) * 128;
  const int wn = ((tid >> 6) & 1) * 64;
  const int l15 = lane & 15, lg = lane >> 4;
  const int srB = tid >> 1, cbB = (tid & 1) << 1;
  f32x4 acc[8][4] = {};

  for (int k0 = 0; k0 < 1024; k0 += 32) {
    const ushort_t* gah = Ah + (size_t)(m0 + tid) * 1024 + k0;
    const ushort_t* gam = Am + (size_t)(m0 + tid) * 1024 + k0;
    const ushort_t* gbh = Bh + (size_t)(n0 + srB) * 1024 + k0 + (cbB << 3);
    const ushort_t* gbm = Bm + (size_t)(n0 + srB) * 1024 + k0 + (cbB << 3);
    uint4 ah4[4], al4[4];
#pragma unroll
    for (int c = 0; c < 4; ++c) { ah4[c] = ((const uint4*)gah)[c]; al4[c] = ((const uint4*)gam)[c]; }
    uint4 b0 = ((const uint4*)gbh)[0], b1 = ((const uint4*)gbh)[1];
    uint4 b2 = ((const uint4*)gbm)[0], b3 = ((const uint4*)gbm)[1];
#pragma unroll
    for (int c = 0; c < 4; ++c) {
      *(uint4*)(&Ash[tid][SWZ_COL(tid, c)]) = ah4[c];
      *(uint4*)(&Asl[tid][SWZ_COL(tid, c)]) = al4[c];
    }
    *(uint4*)(&Bsh[srB][SWZ_COL(srB, cbB)]) = b0;
    *(uint4*)(&Bsh[srB][SWZ_COL(srB, cbB + 1)]) = b1;
    *(uint4*)(&Bsl[srB][SWZ_COL(srB, cbB)]) = b2;
    *(uint4*)(&Bsl[srB][SWZ_COL(srB, cbB + 1)]) = b3;
    __syncthreads();
    frag8 ah[8], al[8];
#pragma unroll
    for (int i = 0; i < 8; ++i) {
      int rA = wm + i * 16 + l15;
      int cA = SWZ_COL(rA, lg);
      ah[i] = *(const frag8*)(&Ash[rA][cA]);
      al[i] = *(const frag8*)(&Asl[rA][cA]);
    }
#pragma unroll
    for (int ni = 0; ni < 4; ++ni) {
      int rB = wn + ni * 16 + l15;
      int cB = SWZ_COL(rB, lg);
      frag8 bh = *(const frag8*)(&Bsh[rB][cB]);
      frag8 bl = *(const frag8*)(&Bsl[rB][cB]);
#pragma unroll
      for (int mi = 0; mi < 8; ++mi) {
        acc[mi][ni] = __builtin_amdgcn_mfma_f32_16x16x32_bf16(ah[mi], bh, acc[mi][ni], 0, 0, 0);
        acc[mi][ni] = __builtin_amdgcn_mfma_f32_16x16x32_bf16(ah[mi], bl, acc[mi][ni], 0, 0, 0);
        acc[mi][ni] = __builtin_amdgcn_mfma_f32_16x16x32_bf16(al[mi], bh, acc[mi][ni], 0, 0, 0);
      }
    }
    __syncthreads();
  }

  const float* scale = (mat == 0) ? qn : (mat == 1 ? kn : nullptr);
  ushort_t* outh = (mat == 0) ? qh : (mat == 1 ? kh : vh);
  ushort_t* outm = (mat == 0) ? qm : (mat == 1 ? km : vm);
  const float inv = powf(10000.f, -(float)l15 * (1.f / 16.f));
#pragma unroll
  for (int mi = 0; mi < 8; ++mi) {
#pragma unroll
    for (int rr = 0; rr < 4; ++rr) {
      float ss = 0.f;
#pragma unroll
      for (int ni = 0; ni < 4; ++ni) { float v = acc[mi][ni][rr]; ss += v * v; }
      ss += __shfl_xor(ss, 1);
      ss += __shfl_xor(ss, 2);
      ss += __shfl_xor(ss, 4);
      ss += __shfl_xor(ss, 8);
      float rs = rsqrtf(ss * (1.f / 64.f) + 1e-6f);
      int row = m0 + wm + mi * 16 + (lg << 2) + rr;
      float nv[4];
#pragma unroll
      for (int ni = 0; ni < 4; ++ni) {
        float sc = scale ? scale[ni * 16 + l15] : 1.f;
        nv[ni] = acc[mi][ni][rr] * rs * sc;
      }
      if (mat < 2) {
        int p0 = pos[(size_t)row * 2], p1 = pos[(size_t)row * 2 + 1];
        p0 = p0 > 0 ? p0 : 0;
        p1 = p1 > 0 ? p1 : 0;
        float a0 = (float)p0 * inv, a1 = (float)p1 * inv;
        float c0 = cosf(a0), s0 = sinf(a0);
        float c1 = cosf(a1), s1 = sinf(a1);
        float t0 = nv[0] * c0 - nv[1] * s0;
        float t1 = nv[1] * c0 + nv[0] * s0;
        float t2 = nv[2] * c1 - nv[3] * s1;
        float t3 = nv[3] * c1 + nv[2] * s1;
        nv[0] = t0; nv[1] = t1; nv[2] = t2; nv[3] = t3;
      }
#pragma unroll
      for (int ni = 0; ni < 4; ++ni) {
        ushort_t h, m;
        splitf(nv[ni], h, m);
        size_t idx = (size_t)row * 1024 + n0 + wn + ni * 16 + l15;
        outh[idx] = h;
        outm[idx] = m;
      }
    }
  }
}

// ================= fused FFW up: gelu(h@Wg)*(h@Wu) (unchanged, verified) =================
__global__ __launch_bounds__(256) void k_ffw_up(const ushort_t* __restrict__ Ah,
                                                const ushort_t* __restrict__ Am,
                                                const ushort_t* __restrict__ Gh,
                                                const ushort_t* __restrict__ Gm,
                                                const ushort_t* __restrict__ Uh,
                                                const ushort_t* __restrict__ Um,
                                                ushort_t* __restrict__ Oh,
                                                ushort_t* __restrict__ Om) {
  __shared__ __align__(16) ushort_t Ash[128][40];
  __shared__ __align__(16) ushort_t Asl[128][40];
  __shared__ __align__(16) ushort_t Bgh[128][40];
  __shared__ __align__(16) ushort_t Bgl[128][40];
  __shared__ __align__(16) ushort_t Buh[128][40];
  __shared__ __align__(16) ushort_t Bul[128][40];
  const int tid = threadIdx.x;
  const int bid = blockIdx.x;
  const int xcd = bid & 7, lo = bid >> 3;
  const int nt = xcd * 4 + (lo & 3);
  const int mt = lo >> 2;
  const int m0 = mt << 7, n0 = nt << 7;
  const int lane = tid & 63;
  const int wm = ((tid >> 7) & 1) * 64;
  const int wn = ((tid >> 6) & 1) * 64;
  const int l15 = lane & 15, lg = lane >> 4;
  const int srow = tid >> 1, scol = (tid & 1) << 4;
  const int cb = (tid & 1) << 1;
  const int wc0 = SWZ_COL(srow, cb), wc1 = SWZ_COL(srow, cb + 1);
  f32x4 ag[4][4] = {};
  f32x4 au[4][4] = {};

  for (int k0 = 0; k0 < 1024; k0 += 32) {
    const ushort_t* gah = Ah + (size_t)(m0 + srow) * 1024 + k0 + scol;
    const ushort_t* gam = Am + (size_t)(m0 + srow) * 1024 + k0 + scol;
    const ushort_t* ggh = Gh + (size_t)(n0 + srow) * 1024 + k0 + scol;
    const ushort_t* ggm = Gm + (size_t)(n0 + srow) * 1024 + k0 + scol;
    const ushort_t* guh = Uh + (size_t)(n0 + srow) * 1024 + k0 + scol;
    const ushort_t* gum = Um + (size_t)(n0 + srow) * 1024 + k0 + scol;
    uint4 a0 = *(const uint4*)gah, a1 = *(const uint4*)(gah + 8);
    uint4 a2 = *(const uint4*)gam, a3 = *(const uint4*)(gam + 8);
    uint4 g0 = *(const uint4*)ggh, g1 = *(const uint4*)(ggh + 8);
    uint4 g2 = *(const uint4*)ggm, g3 = *(const uint4*)(ggm + 8);
    uint4 u0 = *(const uint4*)guh, u1 = *(const uint4*)(guh + 8);
    uint4 u2 = *(const uint4*)gum, u3 = *(const uint4*)(gum + 8);
    *(uint4*)(&Ash[srow][wc0]) = a0;
    *(uint4*)(&Ash[srow][wc1]) = a1;
    *(uint4*)(&Asl[srow][wc0]) = a2;
    *(uint4*)(&Asl[srow][wc1]) = a3;
    *(uint4*)(&Bgh[srow][wc0]) = g0;
    *(uint4*)(&Bgh[srow][wc1]) = g1;
    *(uint4*)(&Bgl[srow][wc0]) = g2;
    *(uint4*)(&Bgl[srow][wc1]) = g3;
    *(uint4*)(&Buh[srow][wc0]) = u0;
    *(uint4*)(&Buh[srow][wc1]) = u1;
    *(uint4*)(&Bul[srow][wc0]) = u2;
    *(uint4*)(&Bul[srow][wc1]) = u3;
    __syncthreads();
    frag8 ah[4], al[4];
#pragma unroll
    for (int i = 0; i < 4; ++i) {
      int rA = wm + i * 16 + l15;
      int cA = SWZ_COL(rA, lg);
      ah[i] = *(const frag8*)(&Ash[rA][cA]);
      al[i] = *(const frag8*)(&Asl[rA][cA]);
    }
#pragma unroll
    for (int ni = 0; ni < 4; ++ni) {
      int rB = wn + ni * 16 + l15;
      int cB = SWZ_COL(rB, lg);
      frag8 bgh = *(const frag8*)(&Bgh[rB][cB]);
      frag8 bgl = *(const frag8*)(&Bgl[rB][cB]);
      frag8 buh = *(const frag8*)(&Buh[rB][cB]);
      frag8 bul = *(const frag8*)(&Bul[rB][cB]);
#pragma unroll
      for (int mi = 0; mi < 4; ++mi) {
        ag[mi][ni] = __builtin_amdgcn_mfma_f32_16x16x32_bf16(ah[mi], bgh, ag[mi][ni], 0, 0, 0);
        ag[mi][ni] = __builtin_amdgcn_mfma_f32_16x16x32_bf16(ah[mi], bgl, ag[mi][ni], 0, 0, 0);
        ag[mi][ni] = __builtin_amdgcn_mfma_f32_16x16x32_bf16(al[mi], bgh, ag[mi][ni], 0, 0, 0);
        au[mi][ni] = __builtin_amdgcn_mfma_f32_16x16x32_bf16(ah[mi], buh, au[mi][ni], 0, 0, 0);
        au[mi][ni] = __builtin_amdgcn_mfma_f32_16x16x32_bf16(ah[mi], bul, au[mi][ni], 0, 0, 0);
        au[mi][ni] = __builtin_amdgcn_mfma_f32_16x16x32_bf16(al[mi], buh, au[mi][ni], 0, 0, 0);
      }
    }
    __syncthreads();
  }

#pragma unroll
  for (int mi = 0; mi < 4; ++mi) {
#pragma unroll
    for (int ni = 0; ni < 4; ++ni) {
#pragma unroll
      for (int r = 0; r < 4; ++r) {
        float vg = ag[mi][ni][r];
        float x3 = vg * vg * vg;
        float gel = 0.5f * vg * (1.f + tanhf(0.7978845608028654f * (vg + 0.044715f * x3)));
        float v2 = gel * au[mi][ni][r];
        int gr = m0 + wm + mi * 16 + (lg << 2) + r;
        int gc = n0 + wn + ni * 16 + l15;
        size_t idx = (size_t)gr * 4096 + gc;
        ushort_t h, m;
        splitf(v2, h, m);
        Oh[idx] = h;
        Om[idx] = m;
      }
    }
  }
}

// ---------------- split GEMM, 256x128 tile (mi=8), K-split capable ----------------
enum { EPI_F32 = 0, EPI_ADDF32 = 1 };

template <int EPI>
__global__ __launch_bounds__(256, 2) void k_gemm_s(const ushort_t* __restrict__ Ah,
                                                   const ushort_t* __restrict__ Am,
                                                   const ushort_t* __restrict__ Bh,
                                                   const ushort_t* __restrict__ Bm,
                                                   float* C0, float* C1,
                                                   int K, int N, int ksteps) {
  __shared__ __align__(16) ushort_t Ash[256][40];
  __shared__ __align__(16) ushort_t Asl[256][40];
  __shared__ __align__(16) ushort_t Bsh[128][40];
  __shared__ __align__(16) ushort_t Bsl[128][40];
  const int tid = threadIdx.x;
  const int bid = blockIdx.x;
  const int half = bid >> 7;         // 128 inner blocks per K-half
  const int inner = bid & 127;
  float* Cf = half ? C1 : C0;
  const int kbase = half * ksteps * 32;
  const int xcd = inner & 7, lo = inner >> 3;   // lo 0..15
  const int mt = xcd * 2 + (lo >> 3);           // 16 m-tiles of 256
  const int nt = lo & 7;
  const int m0 = mt << 8, n0 = nt << 7;
  const int lane = tid & 63;
  const int wm = ((tid >> 7) & 1) * 128;
  const int wn = ((tid >> 6) & 1) * 64;
  const int l15 = lane & 15, lg = lane >> 4;
  const int srB = tid >> 1, cbB = (tid & 1) << 1;
  f32x4 acc[8][4] = {};

  for (int ks = 0; ks < ksteps; ++ks) {
    const int k0 = kbase + ks * 32;
    const ushort_t* gah = Ah + (size_t)(m0 + tid) * K + k0;
    const ushort_t* gam = Am + (size_t)(m0 + tid) * K + k0;
    const ushort_t* gbh = Bh + (size_t)(n0 + srB) * K + k0 + (cbB << 3);
    const ushort_t* gbm = Bm + (size_t)(n0 + srB) * K + k0 + (cbB << 3);
    uint4 ah4[4], al4[4];
#pragma unroll
    for (int c = 0; c < 4; ++c) { ah4[c] = ((const uint4*)gah)[c]; al4[c] = ((const uint4*)gam)[c]; }
    uint4 b0 = ((const uint4*)gbh)[0], b1 = ((const uint4*)gbh)[1];
    uint4 b2 = ((const uint4*)gbm)[0], b3 = ((const uint4*)gbm)[1];
#pragma unroll
    for (int c = 0; c < 4; ++c) {
      *(uint4*)(&Ash[tid][SWZ_COL(tid, c)]) = ah4[c];
      *(uint4*)(&Asl[tid][SWZ_COL(tid, c)]) = al4[c];
    }
    *(uint4*)(&Bsh[srB][SWZ_COL(srB, cbB)]) = b0;
    *(uint4*)(&Bsh[srB][SWZ_COL(srB, cbB + 1)]) = b1;
    *(uint4*)(&Bsl[srB][SWZ_COL(srB, cbB)]) = b2;
    *(uint4*)(&Bsl[srB][SWZ_COL(srB, cbB + 1)]) = b3;
    __syncthreads();
    frag8 ah[8], al[8];
#pragma unroll
    for (int i = 0; i < 8; ++i) {
      int rA = wm + i * 16 + l15;
      int cA = SWZ_COL(rA, lg);
      ah[i] = *(const frag8*)(&Ash[rA][cA]);
      al[i] = *(const frag8*)(&Asl[rA][cA]);
    }
#pragma unroll
    for (int ni = 0; ni < 4; ++ni) {
      int rB = wn + ni * 16 + l15;
      int cB = SWZ_COL(rB, lg);
      frag8 bh = *(const frag8*)(&Bsh[rB][cB]);
      frag8 bl = *(const frag8*)(&Bsl[rB][cB]);
#pragma unroll
      for (int mi = 0; mi < 8; ++mi) {
        acc[mi][ni] = __builtin_amdgcn_mfma_f32_16x16x32_bf16(ah[mi], bh, acc[mi][ni], 0, 0, 0);
        acc[mi][ni] = __builtin_amdgcn_mfma_f32_16x16x32_bf16(ah[mi], bl, acc[mi][ni], 0, 0, 0);
        acc[mi][ni] = __builtin_amdgcn_mfma_f32_16x16x32_bf16(al[mi], bh, acc[mi][ni], 0, 0, 0);
      }
    }
    __syncthreads();
  }

#pragma unroll
  for (int mi = 0; mi < 8; ++mi) {
#pragma unroll
    for (int ni = 0; ni < 4; ++ni) {
#pragma unroll
      for (int r = 0; r < 4; ++r) {
        float val = acc[mi][ni][r];
        int gr = m0 + wm + mi * 16 + (lg << 2) + r;
        int gc = n0 + wn + ni * 16 + l15;
        size_t idx = (size_t)gr * N + gc;
        if (EPI == EPI_F32) Cf[idx] = val;
        else Cf[idx] += val;
      }
    }
  }
}

// ---------------- split-bf16 MFMA flash attention (unchanged, verified) ----------------
__global__ __launch_bounds__(256) void k_attn_s(const ushort_t* __restrict__ qh,
                                                const ushort_t* __restrict__ qm,
                                                const ushort_t* __restrict__ kh,
                                                const ushort_t* __restrict__ km,
                                                const ushort_t* __restrict__ vh,
                                                const ushort_t* __restrict__ vm,
                                                ushort_t* __restrict__ oh,
                                                ushort_t* __restrict__ om) {
  __shared__ __align__(16) ushort_t Khs[64][72];
  __shared__ __align__(16) ushort_t Kms[64][72];
  __shared__ __align__(16) ushort_t Vhs[64][72];
  __shared__ __align__(16) ushort_t Vms[64][72];
  __shared__ __align__(16) ushort_t Phs[64][72];
  __shared__ __align__(16) ushort_t Pms[64][72];
  const int tid = threadIdx.x;
  const int bid = blockIdx.x;
  const int xcd = bid & 7, lo = bid >> 3;
  const int bh_ = xcd * 8 + (lo >> 4);
  const int qt = lo & 15;
  const int b = bh_ >> 4, n = bh_ & 15;
  const size_t base = (size_t)b * 1048576 + (size_t)n * 64;
  const int lane = tid & 63, w = tid >> 6;
  const int l15 = lane & 15, lg = lane >> 4;

  {
    int row = tid >> 2, cg = (tid & 3) << 4;
    const uint4* sh = (const uint4*)(qh + base + (size_t)(qt * 64 + row) * 1024 + cg);
    const uint4* sm = (const uint4*)(qm + base + (size_t)(qt * 64 + row) * 1024 + cg);
    uint4 h0 = sh[0], h1 = sh[1], m0v = sm[0], m1v = sm[1];
    *(uint4*)(&Khs[row][cg]) = h0;
    *(uint4*)(&Khs[row][cg + 8]) = h1;
    *(uint4*)(&Kms[row][cg]) = m0v;
    *(uint4*)(&Kms[row][cg + 8]) = m1v;
  }
  __syncthreads();
  frag8 qh0 = *(const frag8*)(&Khs[w * 16 + l15][lg << 3]);
  frag8 qh1 = *(const frag8*)(&Khs[w * 16 + l15][32 + (lg << 3)]);
  frag8 qm0 = *(const frag8*)(&Kms[w * 16 + l15][lg << 3]);
  frag8 qm1 = *(const frag8*)(&Kms[w * 16 + l15][32 + (lg << 3)]);

  f32x4 oacc[4] = {};
  float mrun[4], srun[4];
#pragma unroll
  for (int r = 0; r < 4; ++r) { mrun[r] = -3.0e38f; srun[r] = 0.f; }

  for (int t = 0; t < 16; ++t) {
    __syncthreads();
    {
      int row = tid >> 2, cg = (tid & 3) << 4;
      const uint4* sh = (const uint4*)(kh + base + (size_t)(t * 64 + row) * 1024 + cg);
      const uint4* sm = (const uint4*)(km + base + (size_t)(t * 64 + row) * 1024 + cg);
      uint4 h0 = sh[0], h1 = sh[1], m0v = sm[0], m1v = sm[1];
      *(uint4*)(&Khs[row][cg]) = h0;
      *(uint4*)(&Khs[row][cg + 8]) = h1;
      *(uint4*)(&Kms[row][cg]) = m0v;
      *(uint4*)(&Kms[row][cg + 8]) = m1v;
    }
    {
      int hcol = tid & 63, kg = tid >> 6;
      ushort_t th[16], tm_[16];
#pragma unroll
      for (int j = 0; j < 16; ++j) {
        size_t off = base + (size_t)(t * 64 + kg * 16 + j) * 1024 + hcol;
        th[j] = vh[off];
        tm_[j] = vm[off];
      }
#pragma unroll
      for (int g = 0; g < 4; ++g) {
        ushort4 wv, wv2;
        wv.x = th[g * 4]; wv.y = th[g * 4 + 1]; wv.z = th[g * 4 + 2]; wv.w = th[g * 4 + 3];
        wv2.x = tm_[g * 4]; wv2.y = tm_[g * 4 + 1]; wv2.z = tm_[g * 4 + 2]; wv2.w = tm_[g * 4 + 3];
        *(ushort4*)(&Vhs[hcol][kg * 16 + g * 4]) = wv;
        *(ushort4*)(&Vms[hcol][kg * 16 + g * 4]) = wv2;
      }
    }
    __syncthreads();

    f32x4 sacc[4] = {};
#pragma unroll
    for (int nf = 0; nf < 4; ++nf) {
      frag8 kh0 = *(const frag8*)(&Khs[nf * 16 + l15][lg << 3]);
      frag8 kh1 = *(const frag8*)(&Khs[nf * 16 + l15][32 + (lg << 3)]);
      frag8 km0 = *(const frag8*)(&Kms[nf * 16 + l15][lg << 3]);
      frag8 km1 = *(const frag8*)(&Kms[nf * 16 + l15][32 + (lg << 3)]);
      sacc[nf] = __builtin_amdgcn_mfma_f32_16x16x32_bf16(qh0, kh0, sacc[nf], 0, 0, 0);
      sacc[nf] = __builtin_amdgcn_mfma_f32_16x16x32_bf16(qh1, kh1, sacc[nf], 0, 0, 0);
      sacc[nf] = __builtin_amdgcn_mfma_f32_16x16x32_bf16(qh0, km0, sacc[nf], 0, 0, 0);
      sacc[nf] = __builtin_amdgcn_mfma_f32_16x16x32_bf16(qh1, km1, sacc[nf], 0, 0, 0);
      sacc[nf] = __builtin_amdgcn_mfma_f32_16x16x32_bf16(qm0, kh0, sacc[nf], 0, 0, 0);
      sacc[nf] = __builtin_amdgcn_mfma_f32_16x16x32_bf16(qm1, kh1, sacc[nf], 0, 0, 0);
    }
#pragma unroll
    for (int r = 0; r < 4; ++r) {
      float tm = fmaxf(fmaxf(sacc[0][r], sacc[1][r]), fmaxf(sacc[2][r], sacc[3][r]));
      tm = fmaxf(tm, __shfl_xor(tm, 1));
      tm = fmaxf(tm, __shfl_xor(tm, 2));
      tm = fmaxf(tm, __shfl_xor(tm, 4));
      tm = fmaxf(tm, __shfl_xor(tm, 8));
      float nm = fmaxf(mrun[r], tm);
      float al = expf(mrun[r] - nm);
      float p0 = expf(sacc[0][r] - nm);
      float p1 = expf(sacc[1][r] - nm);
      float p2 = expf(sacc[2][r] - nm);
      float p3 = expf(sacc[3][r] - nm);
      float rs = p0 + p1 + p2 + p3;
      rs += __shfl_xor(rs, 1);
      rs += __shfl_xor(rs, 2);
      rs += __shfl_xor(rs, 4);
      rs += __shfl_xor(rs, 8);
      srun[r] = srun[r] * al + rs;
      mrun[r] = nm;
#pragma unroll
      for (int hf = 0; hf < 4; ++hf) oacc[hf][r] *= al;
      int prow = w * 16 + lg * 4 + r;
      ushort_t ph, pm;
      splitf(p0, ph, pm); Phs[prow][0 * 16 + l15] = ph; Pms[prow][0 * 16 + l15] = pm;
      splitf(p1, ph, pm); Phs[prow][1 * 16 + l15] = ph; Pms[prow][1 * 16 + l15] = pm;
      splitf(p2, ph, pm); Phs[prow][2 * 16 + l15] = ph; Pms[prow][2 * 16 + l15] = pm;
      splitf(p3, ph, pm); Phs[prow][3 * 16 + l15] = ph; Pms[prow][3 * 16 + l15] = pm;
    }
    __syncthreads();
#pragma unroll
    for (int kg = 0; kg < 2; ++kg) {
      frag8 pf = *(const frag8*)(&Phs[w * 16 + l15][kg * 32 + (lg << 3)]);
      frag8 pf2 = *(const frag8*)(&Pms[w * 16 + l15][kg * 32 + (lg << 3)]);
#pragma unroll
      for (int hf = 0; hf < 4; ++hf) {
        frag8 vf = *(const frag8*)(&Vhs[hf * 16 + l15][kg * 32 + (lg << 3)]);
        frag8 vf2 = *(const frag8*)(&Vms[hf * 16 + l15][kg * 32 + (lg << 3)]);
        oacc[hf] = __builtin_amdgcn_mfma_f32_16x16x32_bf16(pf, vf, oacc[hf], 0, 0, 0);
        oacc[hf] = __builtin_amdgcn_mfma_f32_16x16x32_bf16(pf, vf2, oacc[hf], 0, 0, 0);
        oacc[hf] = __builtin_amdgcn_mfma_f32_16x16x32_bf16(pf2, vf, oacc[hf], 0, 0, 0);
      }
    }
  }
#pragma unroll
  for (int hf = 0; hf < 4; ++hf)
#pragma unroll
    for (int r = 0; r < 4; ++r) {
      float val = oacc[hf][r] / srun[r];
      size_t off = base + (size_t)(qt * 64 + w * 16 + lg * 4 + r) * 1024 + hf * 16 + l15;
      ushort_t h, m;
      splitf(val, h, m);
      oh[off] = h;
      om[off] = m;
    }
}

// ---------------- 4x4 pooling + mask ----------------
__global__ __launch_bounds__(256) void k_pool(const float* __restrict__ x,
                                              const int* __restrict__ pos,
                                              float* __restrict__ out,
                                              float* __restrict__ maskout) {
  __shared__ int smax[4];
  __shared__ int kidx_s[1024];
  const int blk = blockIdx.x;
  const int b = blk >> 6, oidx = blk & 63;
  const int tid = threadIdx.x;
  int mx = 0;
  for (int l = tid; l < 1024; l += 256) {
    int p0 = pos[((size_t)b * 1024 + l) * 2];
    mx = max(mx, p0 > 0 ? p0 : 0);
  }
  for (int m = 1; m < 64; m <<= 1) mx = max(mx, __shfl_xor(mx, m));
  if ((tid & 63) == 0) smax[tid >> 6] = mx;
  __syncthreads();
  int maxx = max(max(smax[0], smax[1]), max(smax[2], smax[3])) + 1;
  int mk = maxx >> 2;
  for (int l = tid; l < 1024; l += 256) {
    int p0 = pos[((size_t)b * 1024 + l) * 2];
    int p1 = pos[((size_t)b * 1024 + l) * 2 + 1];
    int c0 = p0 > 0 ? p0 : 0, c1 = p1 > 0 ? p1 : 0;
    int pad = (p0 == -1 && p1 == -1) ? 1 : 0;
    kidx_s[l] = ((c0 >> 2) + mk * (c1 >> 2)) | (pad << 16);
  }
  __syncthreads();
  float ax = 0.f, ay = 0.f, az = 0.f, aw = 0.f;
  int cnt = 0;
  for (int l = 0; l < 1024; ++l) {
    int ki = kidx_s[l];
    if ((ki & 0xffff) == oidx) {
      cnt++;
      if (!(ki >> 16)) {
        float4 xv = ((const float4*)(x + ((size_t)b * 1024 + l) * 1024))[tid];
        ax += xv.x; ay += xv.y; az += xv.z; aw += xv.w;
      }
    }
  }
  float4 res;
  res.x = ax * 2.0f; res.y = ay * 2.0f; res.z = az * 2.0f; res.w = aw * 2.0f;
  ((float4*)(out + ((size_t)b * 64 + oidx) * 1024))[tid] = res;
  if (tid == 0) maskout[b * 64 + oidx] = (cnt > 0) ? 1.0f : 0.0f;
}

// ---------------- host launch ----------------
extern "C" void kernel_launch(void* const* d_in, const int* in_sizes, int n_in,
                              void* d_out, int out_size, void* d_ws, size_t ws_size,
                              hipStream_t stream) {
  const float* pix = (const float*)d_in[0];
  const int* pos = (const int*)d_in[1];
  const float* Win = (const float*)d_in[2];
  const float* ptab = (const float*)d_in[3];
  const float* Wq = (const float*)d_in[4];
  const float* Wk = (const float*)d_in[5];
  const float* Wv = (const float*)d_in[6];
  const float* Wo = (const float*)d_in[7];
  const float* qn = (const float*)d_in[8];
  const float* kn = (const float*)d_in[9];
  const float* pre_attn = (const float*)d_in[10];
  const float* post_attn = (const float*)d_in[11];
  const float* pre_ffw = (const float*)d_in[12];
  const float* post_ffw = (const float*)d_in[13];
  const float* Wg = (const float*)d_in[14];
  const float* Wu = (const float*)d_in[15];
  const float* Wd = (const float*)d_in[16];

  char* w = (char*)d_ws;
  float* x = (float*)w;        w += 16777216;
  float* tmp = (float*)w;      w += 16777216;
  ushort_t* hh = (ushort_t*)w; w += 8388608;
  ushort_t* hm = (ushort_t*)w; w += 8388608;
  char* regB = w;  // 128 MiB overlapped region
  ushort_t* qh_ = (ushort_t*)(regB + 0);
  ushort_t* qm_ = (ushort_t*)(regB + 8388608);
  ushort_t* kh_ = (ushort_t*)(regB + 16777216);
  ushort_t* km_ = (ushort_t*)(regB + 25165824);
  ushort_t* vh_ = (ushort_t*)(regB + 33554432);
  ushort_t* vm_ = (ushort_t*)(regB + 41943040);
  ushort_t* aoh = (ushort_t*)(regB + 50331648);
  ushort_t* aom = (ushort_t*)(regB + 58720256);
  ushort_t* wat_h = (ushort_t*)(regB + 67108864);
  ushort_t* wat_m = (ushort_t*)(regB + 75497472);
  float* t2o = (float*)(regB + 0);
  ushort_t* mh = (ushort_t*)(regB + 0);
  ushort_t* mm = (ushort_t*)(regB + 33554432);
  ushort_t* wgu_h = (ushort_t*)(regB + 67108864);
  ushort_t* wgu_m = (ushort_t*)(regB + 83886080);
  ushort_t* wd_h = (ushort_t*)(regB + 100663296);
  ushort_t* wd_m = (ushort_t*)(regB + 109051904);
  float* t2d = (float*)(regB + 67108864);
  ushort_t* pixh = (ushort_t*)(regB + 0);
  ushort_t* pixm = (ushort_t*)(regB + 6291456);
  ushort_t* win_h = (ushort_t*)(regB + 67108864);
  ushort_t* win_m = (ushort_t*)(regB + 71303168);

  dim3 blk(256);
  k_splitpix<<<3072, blk, 0, stream>>>(pix, pixh, pixm, 786432);
  k_posemb<<<4096, blk, 0, stream>>>(pos, ptab, x);
  k_wsplit4<<<dim3(16, 12, 1), blk, 0, stream>>>(Win, Win, Win, Win, win_h, win_m, 768, 1024);
  k_gemm_s<EPI_ADDF32><<<128, blk, 0, stream>>>(pixh, pixm, win_h, win_m, x, nullptr,
                                                768, 1024, 24);

  for (int i = 0; i < 6; ++i) {
    const float* wq = Wq + (size_t)i * 1048576;
    const float* wk = Wk + (size_t)i * 1048576;
    const float* wv = Wv + (size_t)i * 1048576;
    const float* wo = Wo + (size_t)i * 1048576;
    const float* wg = Wg + (size_t)i * 4194304;
    const float* wu = Wu + (size_t)i * 4194304;
    const float* wd = Wd + (size_t)i * 4194304;

    k_rmsnorm_s<<<4096, blk, 0, stream>>>(x, pre_attn + i * 1024, hh, hm);
    k_wsplit4<<<dim3(16, 16, 4), blk, 0, stream>>>(wq, wk, wv, wo, wat_h, wat_m, 1024, 1024);
    k_qkv<<<384, blk, 0, stream>>>(hh, hm, wat_h, wat_m, qn + i * 64, kn + i * 64, pos,
                                   qh_, qm_, kh_, km_, vh_, vm_);
    k_attn_s<<<1024, blk, 0, stream>>>(qh_, qm_, kh_, km_, vh_, vm_, aoh, aom);
    k_gemm_s<EPI_F32><<<256, blk, 0, stream>>>(aoh, aom, wat_h + 3145728, wat_m + 3145728,
                                               tmp, t2o, 1024, 1024, 16);
    k_addrms32<<<4096, blk, 0, stream>>>(x, tmp, t2o, post_attn + i * 1024);

    k_rmsnorm_s<<<4096, blk, 0, stream>>>(x, pre_ffw + i * 1024, hh, hm);
    k_wsplit4<<<dim3(64, 16, 2), blk, 0, stream>>>(wg, wu, wg, wu, wgu_h, wgu_m, 1024, 4096);
    k_wsplit4<<<dim3(16, 64, 1), blk, 0, stream>>>(wd, wd, wd, wd, wd_h, wd_m, 4096, 1024);
    k_ffw_up<<<1024, blk, 0, stream>>>(hh, hm, wgu_h, wgu_m, wgu_h + 4194304, wgu_m + 4194304,
                                       mh, mm);
    k_gemm_s<EPI_F32><<<256, blk, 0, stream>>>(mh, mm, wd_h, wd_m, tmp, t2d, 4096, 1024, 64);
    k_addrms32<<<4096, blk, 0, stream>>>(x, tmp, t2d, post_ffw + i * 1024);
  }

  k_pool<<<256, blk, 0, stream>>>(x, pos, (float*)d_out, (float*)d_out + 262144);
}

// Round 13
// 4759.091 us; speedup vs baseline: 1.0831x; 1.0831x over previous
//
#include <hip/hip_runtime.h>
#include <stdint.h>

typedef unsigned short ushort_t;
using frag8 = __attribute__((ext_vector_type(8))) short;
using f32x4 = __attribute__((ext_vector_type(4))) float;

static __device__ __forceinline__ unsigned short f2bf(float f) {
  union { float f; unsigned u; } v; v.f = f;
  unsigned r = v.u + 0x7fffu + ((v.u >> 16) & 1u);
  return (unsigned short)(r >> 16);
}
static __device__ __forceinline__ float bf2f(unsigned short b) {
  union { unsigned u; float f; } v; v.u = ((unsigned)b) << 16; return v.f;
}
static __device__ __forceinline__ void splitf(float v, ushort_t& h, ushort_t& m) {
  h = f2bf(v);
  m = f2bf(v - bf2f(h));
}

// ---------------- pix split ----------------
__global__ __launch_bounds__(256) void k_splitpix(const float* __restrict__ pix,
                                                  ushort_t* __restrict__ oh,
                                                  ushort_t* __restrict__ om, int n4) {
  int i = blockIdx.x * 256 + threadIdx.x;
  if (i >= n4) return;
  float4 v = ((const float4*)pix)[i];
  ushort4 h, m;
  splitf(2.f * (v.x - 0.5f), h.x, m.x);
  splitf(2.f * (v.y - 0.5f), h.y, m.y);
  splitf(2.f * (v.z - 0.5f), h.z, m.z);
  splitf(2.f * (v.w - 0.5f), h.w, m.w);
  ((ushort4*)oh)[i] = h;
  ((ushort4*)om)[i] = m;
}

// ---------------- transpose-split: f32 [K][N] -> bf16 hi/mid [N][K] ----------------
__global__ __launch_bounds__(256) void k_wsplit4(const float* __restrict__ B0,
                                                 const float* __restrict__ B1,
                                                 const float* __restrict__ B2,
                                                 const float* __restrict__ B3,
                                                 ushort_t* __restrict__ th,
                                                 ushort_t* __restrict__ tm,
                                                 int K, int N) {
  __shared__ float ts[64][65];
  const int z = blockIdx.z;
  const float* B = (z == 0) ? B0 : (z == 1) ? B1 : (z == 2) ? B2 : B3;
  th += (size_t)z * K * N;
  tm += (size_t)z * K * N;
  const int tid = threadIdx.x;
  const int n0 = blockIdx.x << 6, k0 = blockIdx.y << 6;
  int rr = tid >> 4, cc = (tid & 15) << 2;
#pragma unroll
  for (int j = 0; j < 4; ++j) {
    int r = rr + j * 16;
    float4 v = *(const float4*)(B + (size_t)(k0 + r) * N + n0 + cc);
    ts[r][cc] = v.x; ts[r][cc + 1] = v.y; ts[r][cc + 2] = v.z; ts[r][cc + 3] = v.w;
  }
  __syncthreads();
  int n = tid >> 2;
  int kc = (tid & 3) << 4;
  ushort_t oh[16], om[16];
#pragma unroll
  for (int j = 0; j < 16; ++j) splitf(ts[kc + j][n], oh[j], om[j]);
  ushort_t* ph = th + (size_t)(n0 + n) * K + k0 + kc;
  ushort_t* pm = tm + (size_t)(n0 + n) * K + k0 + kc;
  *(uint4*)(ph) = *(uint4*)(oh);
  *(uint4*)(ph + 8) = *(uint4*)(oh + 8);
  *(uint4*)(pm) = *(uint4*)(om);
  *(uint4*)(pm + 8) = *(uint4*)(om + 8);
}

// ---------------- pos-emb fill ----------------
__global__ __launch_bounds__(256) void k_posemb(const int* __restrict__ pos,
                                                const float* __restrict__ ptab,
                                                float* __restrict__ x) {
  int row = blockIdx.x, tid = threadIdx.x;
  int p0 = pos[(size_t)row * 2], p1 = pos[(size_t)row * 2 + 1];
  bool pad = (p0 == -1) && (p1 == -1);
  int px = p0 > 0 ? p0 : 0, py = p1 > 0 ? p1 : 0;
  float4 a = ((const float4*)(ptab + (size_t)px * 1024))[tid];
  float4 b = ((const float4*)(ptab + 65536 + (size_t)py * 1024))[tid];
  float4 o;
  o.x = pad ? 0.f : a.x + b.x;
  o.y = pad ? 0.f : a.y + b.y;
  o.z = pad ? 0.f : a.z + b.z;
  o.w = pad ? 0.f : a.w + b.w;
  ((float4*)(x + (size_t)row * 1024))[tid] = o;
}

// ---------------- RMSNorm D=1024: f32 -> hi/mid bf16 ----------------
__global__ __launch_bounds__(256) void k_rmsnorm_s(const float* __restrict__ x,
                                                   const float* __restrict__ scale,
                                                   ushort_t* __restrict__ oh,
                                                   ushort_t* __restrict__ om) {
  __shared__ float wsum[4];
  int row = blockIdx.x, tid = threadIdx.x;
  float4 v = ((const float4*)(x + (size_t)row * 1024))[tid];
  float ss = v.x * v.x + v.y * v.y + v.z * v.z + v.w * v.w;
  for (int m = 1; m < 64; m <<= 1) ss += __shfl_xor(ss, m);
  if ((tid & 63) == 0) wsum[tid >> 6] = ss;
  __syncthreads();
  float tot = wsum[0] + wsum[1] + wsum[2] + wsum[3];
  float r = rsqrtf(tot * (1.f / 1024.f) + 1e-6f);
  float4 sc = ((const float4*)scale)[tid];
  ushort4 h, m;
  splitf(v.x * r * sc.x, h.x, m.x);
  splitf(v.y * r * sc.y, h.y, m.y);
  splitf(v.z * r * sc.z, h.z, m.z);
  splitf(v.w * r * sc.w, h.w, m.w);
  ((ushort4*)(oh + (size_t)row * 1024))[tid] = h;
  ((ushort4*)(om + (size_t)row * 1024))[tid] = m;
}

// ---------------- x += RMSNorm(t1+t2+t3+t4)*scale (f32) ----------------
__global__ __launch_bounds__(256) void k_addrms4(float* __restrict__ x,
                                                 const float* __restrict__ t1,
                                                 const float* __restrict__ t2,
                                                 const float* __restrict__ t3,
                                                 const float* __restrict__ t4,
                                                 const float* __restrict__ scale) {
  __shared__ float wsum[4];
  int row = blockIdx.x, tid = threadIdx.x;
  float4 v = ((const float4*)(t1 + (size_t)row * 1024))[tid];
  float4 v2 = ((const float4*)(t2 + (size_t)row * 1024))[tid];
  float4 v3 = ((const float4*)(t3 + (size_t)row * 1024))[tid];
  float4 v4 = ((const float4*)(t4 + (size_t)row * 1024))[tid];
  v.x += v2.x + v3.x + v4.x;
  v.y += v2.y + v3.y + v4.y;
  v.z += v2.z + v3.z + v4.z;
  v.w += v2.w + v3.w + v4.w;
  float ss = v.x * v.x + v.y * v.y + v.z * v.z + v.w * v.w;
  for (int m = 1; m < 64; m <<= 1) ss += __shfl_xor(ss, m);
  if ((tid & 63) == 0) wsum[tid >> 6] = ss;
  __syncthreads();
  float tot = wsum[0] + wsum[1] + wsum[2] + wsum[3];
  float r = rsqrtf(tot * (1.f / 1024.f) + 1e-6f);
  float4 sc = ((const float4*)scale)[tid];
  float4 xv = ((const float4*)(x + (size_t)row * 1024))[tid];
  xv.x += v.x * r * sc.x;
  xv.y += v.y * r * sc.y;
  xv.z += v.z * r * sc.z;
  xv.w += v.w * r * sc.w;
  ((float4*)(x + (size_t)row * 1024))[tid] = xv;
}

#define SWZ_COL(r, c) (((c) ^ (((r) >> 3) & 3)) << 3)

// ================= fused QKV GEMM + per-head RMS + RoPE (128x128, round-11 proven) =================
__global__ __launch_bounds__(256) void k_qkv(const ushort_t* __restrict__ Ah,
                                             const ushort_t* __restrict__ Am,
                                             const ushort_t* __restrict__ WT_h,
                                             const ushort_t* __restrict__ WT_m,
                                             const float* __restrict__ qn,
                                             const float* __restrict__ kn,
                                             const int* __restrict__ pos,
                                             ushort_t* __restrict__ qh, ushort_t* __restrict__ qm,
                                             ushort_t* __restrict__ kh, ushort_t* __restrict__ km,
                                             ushort_t* __restrict__ vh, ushort_t* __restrict__ vm) {
  __shared__ __align__(16) ushort_t Ash[128][40];
  __shared__ __align__(16) ushort_t Asl[128][40];
  __shared__ __align__(16) ushort_t Bsh[128][40];
  __shared__ __align__(16) ushort_t Bsl[128][40];
  const int tid = threadIdx.x;
  const int bid = blockIdx.x;
  const int xcd = bid & 7, lo = bid >> 3;
  const int ntl = lo % 3, mt = lo / 3;
  const int nt = xcd * 3 + ntl;
  const int mat = nt >> 3;
  const int n0 = (nt & 7) << 7;
  const int m0 = mt << 7;
  const ushort_t* Bh = WT_h + (size_t)mat * 1048576;
  const ushort_t* Bm = WT_m + (size_t)mat * 1048576;

  const int lane = tid & 63;
  const int wm = ((tid >> 7) & 1) * 64;
  const int wn = ((tid >> 6) & 1) * 64;
  const int l15 = lane & 15, lg = lane >> 4;
  const int srow = tid >> 1, scol = (tid & 1) << 4;
  const int cb = (tid & 1) << 1;
  const int wc0 = SWZ_COL(srow, cb), wc1 = SWZ_COL(srow, cb + 1);
  f32x4 acc[4][4] = {};

  for (int k0 = 0; k0 < 1024; k0 += 32) {
    const ushort_t* gah = Ah + (size_t)(m0 + srow) * 1024 + k0 + scol;
    const ushort_t* gam = Am + (size_t)(m0 + srow) * 1024 + k0 + scol;
    const ushort_t* gbh = Bh + (size_t)(n0 + srow) * 1024 + k0 + scol;
    const ushort_t* gbm = Bm + (size_t)(n0 + srow) * 1024 + k0 + scol;
    uint4 a0 = *(const uint4*)gah, a1 = *(const uint4*)(gah + 8);
    uint4 a2 = *(const uint4*)gam, a3 = *(const uint4*)(gam + 8);
    uint4 b0 = *(const uint4*)gbh, b1 = *(const uint4*)(gbh + 8);
    uint4 b2 = *(const uint4*)gbm, b3 = *(const uint4*)(gbm + 8);
    *(uint4*)(&Ash[srow][wc0]) = a0;
    *(uint4*)(&Ash[srow][wc1]) = a1;
    *(uint4*)(&Asl[srow][wc0]) = a2;
    *(uint4*)(&Asl[srow][wc1]) = a3;
    *(uint4*)(&Bsh[srow][wc0]) = b0;
    *(uint4*)(&Bsh[srow][wc1]) = b1;
    *(uint4*)(&Bsl[srow][wc0]) = b2;
    *(uint4*)(&Bsl[srow][wc1]) = b3;
    __syncthreads();
    frag8 ah[4], al[4], bh[4], bl[4];
#pragma unroll
    for (int i = 0; i < 4; ++i) {
      int rA = wm + i * 16 + l15, rB = wn + i * 16 + l15;
      int cA = SWZ_COL(rA, lg), cB = SWZ_COL(rB, lg);
      ah[i] = *(const frag8*)(&Ash[rA][cA]);
      al[i] = *(const frag8*)(&Asl[rA][cA]);
      bh[i] = *(const frag8*)(&Bsh[rB][cB]);
      bl[i] = *(const frag8*)(&Bsl[rB][cB]);
    }
#pragma unroll
    for (int mi = 0; mi < 4; ++mi)
#pragma unroll
      for (int ni = 0; ni < 4; ++ni) {
        acc[mi][ni] = __builtin_amdgcn_mfma_f32_16x16x32_bf16(ah[mi], bh[ni], acc[mi][ni], 0, 0, 0);
        acc[mi][ni] = __builtin_amdgcn_mfma_f32_16x16x32_bf16(ah[mi], bl[ni], acc[mi][ni], 0, 0, 0);
        acc[mi][ni] = __builtin_amdgcn_mfma_f32_16x16x32_bf16(al[mi], bh[ni], acc[mi][ni], 0, 0, 0);
      }
    __syncthreads();
  }

  const float* scale = (mat == 0) ? qn : (mat == 1 ? kn : nullptr);
  ushort_t* outh = (mat == 0) ? qh : (mat == 1 ? kh : vh);
  ushort_t* outm = (mat == 0) ? qm : (mat == 1 ? km : vm);
  const float inv = powf(10000.f, -(float)l15 * (1.f / 16.f));
#pragma unroll
  for (int mi = 0; mi < 4; ++mi) {
#pragma unroll
    for (int rr = 0; rr < 4; ++rr) {
      float ss = 0.f;
#pragma unroll
      for (int ni = 0; ni < 4; ++ni) { float v = acc[mi][ni][rr]; ss += v * v; }
      ss += __shfl_xor(ss, 1);
      ss += __shfl_xor(ss, 2);
      ss += __shfl_xor(ss, 4);
      ss += __shfl_xor(ss, 8);
      float rs = rsqrtf(ss * (1.f / 64.f) + 1e-6f);
      int row = m0 + wm + mi * 16 + (lg << 2) + rr;
      float nv[4];
#pragma unroll
      for (int ni = 0; ni < 4; ++ni) {
        float sc = scale ? scale[ni * 16 + l15] : 1.f;
        nv[ni] = acc[mi][ni][rr] * rs * sc;
      }
      if (mat < 2) {
        int p0 = pos[(size_t)row * 2], p1 = pos[(size_t)row * 2 + 1];
        p0 = p0 > 0 ? p0 : 0;
        p1 = p1 > 0 ? p1 : 0;
        float a0 = (float)p0 * inv, a1 = (float)p1 * inv;
        float c0 = cosf(a0), s0 = sinf(a0);
        float c1 = cosf(a1), s1 = sinf(a1);
        float t0 = nv[0] * c0 - nv[1] * s0;
        float t1 = nv[1] * c0 + nv[0] * s0;
        float t2 = nv[2] * c1 - nv[3] * s1;
        float t3 = nv[3] * c1 + nv[2] * s1;
        nv[0] = t0; nv[1] = t1; nv[2] = t2; nv[3] = t3;
      }
#pragma unroll
      for (int ni = 0; ni < 4; ++ni) {
        ushort_t h, m;
        splitf(nv[ni], h, m);
        size_t idx = (size_t)row * 1024 + n0 + wn + ni * 16 + l15;
        outh[idx] = h;
        outm[idx] = m;
      }
    }
  }
}

// ================= fused FFW up (round-11 proven, unchanged) =================
__global__ __launch_bounds__(256) void k_ffw_up(const ushort_t* __restrict__ Ah,
                                                const ushort_t* __restrict__ Am,
                                                const ushort_t* __restrict__ Gh,
                                                const ushort_t* __restrict__ Gm,
                                                const ushort_t* __restrict__ Uh,
                                                const ushort_t* __restrict__ Um,
                                                ushort_t* __restrict__ Oh,
                                                ushort_t* __restrict__ Om) {
  __shared__ __align__(16) ushort_t Ash[128][40];
  __shared__ __align__(16) ushort_t Asl[128][40];
  __shared__ __align__(16) ushort_t Bgh[128][40];
  __shared__ __align__(16) ushort_t Bgl[128][40];
  __shared__ __align__(16) ushort_t Buh[128][40];
  __shared__ __align__(16) ushort_t Bul[128][40];
  const int tid = threadIdx.x;
  const int bid = blockIdx.x;
  const int xcd = bid & 7, lo = bid >> 3;
  const int nt = xcd * 4 + (lo & 3);
  const int mt = lo >> 2;
  const int m0 = mt << 7, n0 = nt << 7;
  const int lane = tid & 63;
  const int wm = ((tid >> 7) & 1) * 64;
  const int wn = ((tid >> 6) & 1) * 64;
  const int l15 = lane & 15, lg = lane >> 4;
  const int srow = tid >> 1, scol = (tid & 1) << 4;
  const int cb = (tid & 1) << 1;
  const int wc0 = SWZ_COL(srow, cb), wc1 = SWZ_COL(srow, cb + 1);
  f32x4 ag[4][4] = {};
  f32x4 au[4][4] = {};

  for (int k0 = 0; k0 < 1024; k0 += 32) {
    const ushort_t* gah = Ah + (size_t)(m0 + srow) * 1024 + k0 + scol;
    const ushort_t* gam = Am + (size_t)(m0 + srow) * 1024 + k0 + scol;
    const ushort_t* ggh = Gh + (size_t)(n0 + srow) * 1024 + k0 + scol;
    const ushort_t* ggm = Gm + (size_t)(n0 + srow) * 1024 + k0 + scol;
    const ushort_t* guh = Uh + (size_t)(n0 + srow) * 1024 + k0 + scol;
    const ushort_t* gum = Um + (size_t)(n0 + srow) * 1024 + k0 + scol;
    uint4 a0 = *(const uint4*)gah, a1 = *(const uint4*)(gah + 8);
    uint4 a2 = *(const uint4*)gam, a3 = *(const uint4*)(gam + 8);
    uint4 g0 = *(const uint4*)ggh, g1 = *(const uint4*)(ggh + 8);
    uint4 g2 = *(const uint4*)ggm, g3 = *(const uint4*)(ggm + 8);
    uint4 u0 = *(const uint4*)guh, u1 = *(const uint4*)(guh + 8);
    uint4 u2 = *(const uint4*)gum, u3 = *(const uint4*)(gum + 8);
    *(uint4*)(&Ash[srow][wc0]) = a0;
    *(uint4*)(&Ash[srow][wc1]) = a1;
    *(uint4*)(&Asl[srow][wc0]) = a2;
    *(uint4*)(&Asl[srow][wc1]) = a3;
    *(uint4*)(&Bgh[srow][wc0]) = g0;
    *(uint4*)(&Bgh[srow][wc1]) = g1;
    *(uint4*)(&Bgl[srow][wc0]) = g2;
    *(uint4*)(&Bgl[srow][wc1]) = g3;
    *(uint4*)(&Buh[srow][wc0]) = u0;
    *(uint4*)(&Buh[srow][wc1]) = u1;
    *(uint4*)(&Bul[srow][wc0]) = u2;
    *(uint4*)(&Bul[srow][wc1]) = u3;
    __syncthreads();
    frag8 ah[4], al[4];
#pragma unroll
    for (int i = 0; i < 4; ++i) {
      int rA = wm + i * 16 + l15;
      int cA = SWZ_COL(rA, lg);
      ah[i] = *(const frag8*)(&Ash[rA][cA]);
      al[i] = *(const frag8*)(&Asl[rA][cA]);
    }
#pragma unroll
    for (int ni = 0; ni < 4; ++ni) {
      int rB = wn + ni * 16 + l15;
      int cB = SWZ_COL(rB, lg);
      frag8 bgh = *(const frag8*)(&Bgh[rB][cB]);
      frag8 bgl = *(const frag8*)(&Bgl[rB][cB]);
      frag8 buh = *(const frag8*)(&Buh[rB][cB]);
      frag8 bul = *(const frag8*)(&Bul[rB][cB]);
#pragma unroll
      for (int mi = 0; mi < 4; ++mi) {
        ag[mi][ni] = __builtin_amdgcn_mfma_f32_16x16x32_bf16(ah[mi], bgh, ag[mi][ni], 0, 0, 0);
        ag[mi][ni] = __builtin_amdgcn_mfma_f32_16x16x32_bf16(ah[mi], bgl, ag[mi][ni], 0, 0, 0);
        ag[mi][ni] = __builtin_amdgcn_mfma_f32_16x16x32_bf16(al[mi], bgh, ag[mi][ni], 0, 0, 0);
        au[mi][ni] = __builtin_amdgcn_mfma_f32_16x16x32_bf16(ah[mi], buh, au[mi][ni], 0, 0, 0);
        au[mi][ni] = __builtin_amdgcn_mfma_f32_16x16x32_bf16(ah[mi], bul, au[mi][ni], 0, 0, 0);
        au[mi][ni] = __builtin_amdgcn_mfma_f32_16x16x32_bf16(al[mi], buh, au[mi][ni], 0, 0, 0);
      }
    }
    __syncthreads();
  }

#pragma unroll
  for (int mi = 0; mi < 4; ++mi) {
#pragma unroll
    for (int ni = 0; ni < 4; ++ni) {
#pragma unroll
      for (int r = 0; r < 4; ++r) {
        float vg = ag[mi][ni][r];
        float x3 = vg * vg * vg;
        float gel = 0.5f * vg * (1.f + tanhf(0.7978845608028654f * (vg + 0.044715f * x3)));
        float v2 = gel * au[mi][ni][r];
        int gr = m0 + wm + mi * 16 + (lg << 2) + r;
        int gc = n0 + wn + ni * 16 + l15;
        size_t idx = (size_t)gr * 4096 + gc;
        ushort_t h, m;
        splitf(v2, h, m);
        Oh[idx] = h;
        Om[idx] = m;
      }
    }
  }
}

// ---------------- mi=4 split GEMM (embed only, round-11 proven) ----------------
enum { EPI_F32 = 0, EPI_ADDF32 = 1 };

template <int EPI>
__global__ __launch_bounds__(256) void k_gemm_s(const ushort_t* __restrict__ Ah,
                                                const ushort_t* __restrict__ Am,
                                                const ushort_t* __restrict__ Bh,
                                                const ushort_t* __restrict__ Bm,
                                                float* C0, float* C1,
                                                int K, int N, int ksteps) {
  __shared__ __align__(16) ushort_t Ash[128][40];
  __shared__ __align__(16) ushort_t Asl[128][40];
  __shared__ __align__(16) ushort_t Bsh[128][40];
  __shared__ __align__(16) ushort_t Bsl[128][40];
  const int tid = threadIdx.x;
  const int bid = blockIdx.x;
  const int half = bid >> 8;
  const int inner = bid & 255;
  float* Cf = half ? C1 : C0;
  const int kbase = half * ksteps * 32;
  const int xcd = inner & 7, lo = inner >> 3;
  const int mt = xcd * 4 + (lo >> 3);
  const int nt = lo & 7;
  const int m0 = mt << 7, n0 = nt << 7;
  const int lane = tid & 63;
  const int wm = ((tid >> 7) & 1) * 64;
  const int wn = ((tid >> 6) & 1) * 64;
  const int l15 = lane & 15, lg = lane >> 4;
  const int srow = tid >> 1, scol = (tid & 1) << 4;
  const int cb = (tid & 1) << 1;
  const int wc0 = SWZ_COL(srow, cb), wc1 = SWZ_COL(srow, cb + 1);
  f32x4 acc[4][4] = {};

  for (int ks = 0; ks < ksteps; ++ks) {
    const int k0 = kbase + ks * 32;
    const ushort_t* gah = Ah + (size_t)(m0 + srow) * K + k0 + scol;
    const ushort_t* gam = Am + (size_t)(m0 + srow) * K + k0 + scol;
    const ushort_t* gbh = Bh + (size_t)(n0 + srow) * K + k0 + scol;
    const ushort_t* gbm = Bm + (size_t)(n0 + srow) * K + k0 + scol;
    uint4 a0 = *(const uint4*)gah, a1 = *(const uint4*)(gah + 8);
    uint4 a2 = *(const uint4*)gam, a3 = *(const uint4*)(gam + 8);
    uint4 b0 = *(const uint4*)gbh, b1 = *(const uint4*)(gbh + 8);
    uint4 b2 = *(const uint4*)gbm, b3 = *(const uint4*)(gbm + 8);
    *(uint4*)(&Ash[srow][wc0]) = a0;
    *(uint4*)(&Ash[srow][wc1]) = a1;
    *(uint4*)(&Asl[srow][wc0]) = a2;
    *(uint4*)(&Asl[srow][wc1]) = a3;
    *(uint4*)(&Bsh[srow][wc0]) = b0;
    *(uint4*)(&Bsh[srow][wc1]) = b1;
    *(uint4*)(&Bsl[srow][wc0]) = b2;
    *(uint4*)(&Bsl[srow][wc1]) = b3;
    __syncthreads();
    frag8 ah[4], al[4], bh[4], bl[4];
#pragma unroll
    for (int i = 0; i < 4; ++i) {
      int rA = wm + i * 16 + l15, rB = wn + i * 16 + l15;
      int cA = SWZ_COL(rA, lg), cB = SWZ_COL(rB, lg);
      ah[i] = *(const frag8*)(&Ash[rA][cA]);
      al[i] = *(const frag8*)(&Asl[rA][cA]);
      bh[i] = *(const frag8*)(&Bsh[rB][cB]);
      bl[i] = *(const frag8*)(&Bsl[rB][cB]);
    }
#pragma unroll
    for (int mi = 0; mi < 4; ++mi)
#pragma unroll
      for (int ni = 0; ni < 4; ++ni) {
        acc[mi][ni] = __builtin_amdgcn_mfma_f32_16x16x32_bf16(ah[mi], bh[ni], acc[mi][ni], 0, 0, 0);
        acc[mi][ni] = __builtin_amdgcn_mfma_f32_16x16x32_bf16(ah[mi], bl[ni], acc[mi][ni], 0, 0, 0);
        acc[mi][ni] = __builtin_amdgcn_mfma_f32_16x16x32_bf16(al[mi], bh[ni], acc[mi][ni], 0, 0, 0);
      }
    __syncthreads();
  }

#pragma unroll
  for (int mi = 0; mi < 4; ++mi) {
#pragma unroll
    for (int ni = 0; ni < 4; ++ni) {
#pragma unroll
      for (int r = 0; r < 4; ++r) {
        float val = acc[mi][ni][r];
        int gr = m0 + wm + mi * 16 + (lg << 2) + r;
        int gc = n0 + wn + ni * 16 + l15;
        size_t idx = (size_t)gr * N + gc;
        if (EPI == EPI_F32) Cf[idx] = val;
        else Cf[idx] += val;
      }
    }
  }
}

// ---------------- mi=8 register-lean GEMM, 256x128 tile, 4-way K-split ----------------
__global__ __launch_bounds__(256, 2) void k_gemm_s8(const ushort_t* __restrict__ Ah,
                                                    const ushort_t* __restrict__ Am,
                                                    const ushort_t* __restrict__ Bh,
                                                    const ushort_t* __restrict__ Bm,
                                                    float* C0, float* C1, float* C2, float* C3,
                                                    int K, int N, int ksteps) {
  __shared__ __align__(16) ushort_t Ash[256][40];
  __shared__ __align__(16) ushort_t Asl[256][40];
  __shared__ __align__(16) ushort_t Bsh[128][40];
  __shared__ __align__(16) ushort_t Bsl[128][40];
  const int tid = threadIdx.x;
  const int bid = blockIdx.x;          // 512 blocks = 128 tiles x 4 K-quarters
  const int quarter = bid >> 7;
  const int inner = bid & 127;
  float* Cf = (quarter == 0) ? C0 : (quarter == 1) ? C1 : (quarter == 2) ? C2 : C3;
  const int kbase = quarter * ksteps * 32;
  const int xcd = inner & 7, lo = inner >> 3;   // lo 0..15
  const int mt = xcd * 2 + (lo >> 3);           // 16 m-tiles of 256
  const int nt = lo & 7;                        // 8 n-tiles of 128
  const int m0 = mt << 8, n0 = nt << 7;
  const int lane = tid & 63;
  const int wm = ((tid >> 7) & 1) * 128;
  const int wn = ((tid >> 6) & 1) * 64;
  const int l15 = lane & 15, lg = lane >> 4;
  const int srB = tid >> 1, cbB = (tid & 1) << 1;
  f32x4 acc[8][4] = {};

  for (int ks = 0; ks < ksteps; ++ks) {
    const int k0 = kbase + ks * 32;
    const ushort_t* gah = Ah + (size_t)(m0 + tid) * K + k0;
    const ushort_t* gam = Am + (size_t)(m0 + tid) * K + k0;
    const ushort_t* gbh = Bh + (size_t)(n0 + srB) * K + k0 + (cbB << 3);
    const ushort_t* gbm = Bm + (size_t)(n0 + srB) * K + k0 + (cbB << 3);
#pragma unroll
    for (int c = 0; c < 4; ++c) {
      uint4 va = ((const uint4*)gah)[c];
      uint4 vb = ((const uint4*)gam)[c];
      *(uint4*)(&Ash[tid][SWZ_COL(tid, c)]) = va;
      *(uint4*)(&Asl[tid][SWZ_COL(tid, c)]) = vb;
    }
    {
      uint4 b0 = ((const uint4*)gbh)[0], b1 = ((const uint4*)gbh)[1];
      uint4 b2 = ((const uint4*)gbm)[0], b3 = ((const uint4*)gbm)[1];
      *(uint4*)(&Bsh[srB][SWZ_COL(srB, cbB)]) = b0;
      *(uint4*)(&Bsh[srB][SWZ_COL(srB, cbB + 1)]) = b1;
      *(uint4*)(&Bsl[srB][SWZ_COL(srB, cbB)]) = b2;
      *(uint4*)(&Bsl[srB][SWZ_COL(srB, cbB + 1)]) = b3;
    }
    __syncthreads();
    frag8 bh[4], bl[4];
#pragma unroll
    for (int ni = 0; ni < 4; ++ni) {
      int rB = wn + ni * 16 + l15;
      int cB = SWZ_COL(rB, lg);
      bh[ni] = *(const frag8*)(&Bsh[rB][cB]);
      bl[ni] = *(const frag8*)(&Bsl[rB][cB]);
    }
#pragma unroll
    for (int mi = 0; mi < 8; ++mi) {
      int rA = wm + mi * 16 + l15;
      int cA = SWZ_COL(rA, lg);
      frag8 ah = *(const frag8*)(&Ash[rA][cA]);
      frag8 al = *(const frag8*)(&Asl[rA][cA]);
#pragma unroll
      for (int ni = 0; ni < 4; ++ni) {
        acc[mi][ni] = __builtin_amdgcn_mfma_f32_16x16x32_bf16(ah, bh[ni], acc[mi][ni], 0, 0, 0);
        acc[mi][ni] = __builtin_amdgcn_mfma_f32_16x16x32_bf16(ah, bl[ni], acc[mi][ni], 0, 0, 0);
        acc[mi][ni] = __builtin_amdgcn_mfma_f32_16x16x32_bf16(al, bh[ni], acc[mi][ni], 0, 0, 0);
      }
    }
    __syncthreads();
  }

#pragma unroll
  for (int mi = 0; mi < 8; ++mi) {
#pragma unroll
    for (int ni = 0; ni < 4; ++ni) {
#pragma unroll
      for (int r = 0; r < 4; ++r) {
        int gr = m0 + wm + mi * 16 + (lg << 2) + r;
        int gc = n0 + wn + ni * 16 + l15;
        Cf[(size_t)gr * N + gc] = acc[mi][ni][r];
      }
    }
  }
}

// ---------------- split-bf16 MFMA flash attention (unchanged, verified) ----------------
__global__ __launch_bounds__(256) void k_attn_s(const ushort_t* __restrict__ qh,
                                                const ushort_t* __restrict__ qm,
                                                const ushort_t* __restrict__ kh,
                                                const ushort_t* __restrict__ km,
                                                const ushort_t* __restrict__ vh,
                                                const ushort_t* __restrict__ vm,
                                                ushort_t* __restrict__ oh,
                                                ushort_t* __restrict__ om) {
  __shared__ __align__(16) ushort_t Khs[64][72];
  __shared__ __align__(16) ushort_t Kms[64][72];
  __shared__ __align__(16) ushort_t Vhs[64][72];
  __shared__ __align__(16) ushort_t Vms[64][72];
  __shared__ __align__(16) ushort_t Phs[64][72];
  __shared__ __align__(16) ushort_t Pms[64][72];
  const int tid = threadIdx.x;
  const int bid = blockIdx.x;
  const int xcd = bid & 7, lo = bid >> 3;
  const int bh_ = xcd * 8 + (lo >> 4);
  const int qt = lo & 15;
  const int b = bh_ >> 4, n = bh_ & 15;
  const size_t base = (size_t)b * 1048576 + (size_t)n * 64;
  const int lane = tid & 63, w = tid >> 6;
  const int l15 = lane & 15, lg = lane >> 4;

  {
    int row = tid >> 2, cg = (tid & 3) << 4;
    const uint4* sh = (const uint4*)(qh + base + (size_t)(qt * 64 + row) * 1024 + cg);
    const uint4* sm = (const uint4*)(qm + base + (size_t)(qt * 64 + row) * 1024 + cg);
    uint4 h0 = sh[0], h1 = sh[1], m0v = sm[0], m1v = sm[1];
    *(uint4*)(&Khs[row][cg]) = h0;
    *(uint4*)(&Khs[row][cg + 8]) = h1;
    *(uint4*)(&Kms[row][cg]) = m0v;
    *(uint4*)(&Kms[row][cg + 8]) = m1v;
  }
  __syncthreads();
  frag8 qh0 = *(const frag8*)(&Khs[w * 16 + l15][lg << 3]);
  frag8 qh1 = *(const frag8*)(&Khs[w * 16 + l15][32 + (lg << 3)]);
  frag8 qm0 = *(const frag8*)(&Kms[w * 16 + l15][lg << 3]);
  frag8 qm1 = *(const frag8*)(&Kms[w * 16 + l15][32 + (lg << 3)]);

  f32x4 oacc[4] = {};
  float mrun[4], srun[4];
#pragma unroll
  for (int r = 0; r < 4; ++r) { mrun[r] = -3.0e38f; srun[r] = 0.f; }

  for (int t = 0; t < 16; ++t) {
    __syncthreads();
    {
      int row = tid >> 2, cg = (tid & 3) << 4;
      const uint4* sh = (const uint4*)(kh + base + (size_t)(t * 64 + row) * 1024 + cg);
      const uint4* sm = (const uint4*)(km + base + (size_t)(t * 64 + row) * 1024 + cg);
      uint4 h0 = sh[0], h1 = sh[1], m0v = sm[0], m1v = sm[1];
      *(uint4*)(&Khs[row][cg]) = h0;
      *(uint4*)(&Khs[row][cg + 8]) = h1;
      *(uint4*)(&Kms[row][cg]) = m0v;
      *(uint4*)(&Kms[row][cg + 8]) = m1v;
    }
    {
      int hcol = tid & 63, kg = tid >> 6;
      ushort_t th[16], tm_[16];
#pragma unroll
      for (int j = 0; j < 16; ++j) {
        size_t off = base + (size_t)(t * 64 + kg * 16 + j) * 1024 + hcol;
        th[j] = vh[off];
        tm_[j] = vm[off];
      }
#pragma unroll
      for (int g = 0; g < 4; ++g) {
        ushort4 wv, wv2;
        wv.x = th[g * 4]; wv.y = th[g * 4 + 1]; wv.z = th[g * 4 + 2]; wv.w = th[g * 4 + 3];
        wv2.x = tm_[g * 4]; wv2.y = tm_[g * 4 + 1]; wv2.z = tm_[g * 4 + 2]; wv2.w = tm_[g * 4 + 3];
        *(ushort4*)(&Vhs[hcol][kg * 16 + g * 4]) = wv;
        *(ushort4*)(&Vms[hcol][kg * 16 + g * 4]) = wv2;
      }
    }
    __syncthreads();

    f32x4 sacc[4] = {};
#pragma unroll
    for (int nf = 0; nf < 4; ++nf) {
      frag8 kh0 = *(const frag8*)(&Khs[nf * 16 + l15][lg << 3]);
      frag8 kh1 = *(const frag8*)(&Khs[nf * 16 + l15][32 + (lg << 3)]);
      frag8 km0 = *(const frag8*)(&Kms[nf * 16 + l15][lg << 3]);
      frag8 km1 = *(const frag8*)(&Kms[nf * 16 + l15][32 + (lg << 3)]);
      sacc[nf] = __builtin_amdgcn_mfma_f32_16x16x32_bf16(qh0, kh0, sacc[nf], 0, 0, 0);
      sacc[nf] = __builtin_amdgcn_mfma_f32_16x16x32_bf16(qh1, kh1, sacc[nf], 0, 0, 0);
      sacc[nf] = __builtin_amdgcn_mfma_f32_16x16x32_bf16(qh0, km0, sacc[nf], 0, 0, 0);
      sacc[nf] = __builtin_amdgcn_mfma_f32_16x16x32_bf16(qh1, km1, sacc[nf], 0, 0, 0);
      sacc[nf] = __builtin_amdgcn_mfma_f32_16x16x32_bf16(qm0, kh0, sacc[nf], 0, 0, 0);
      sacc[nf] = __builtin_amdgcn_mfma_f32_16x16x32_bf16(qm1, kh1, sacc[nf], 0, 0, 0);
    }
#pragma unroll
    for (int r = 0; r < 4; ++r) {
      float tm = fmaxf(fmaxf(sacc[0][r], sacc[1][r]), fmaxf(sacc[2][r], sacc[3][r]));
      tm = fmaxf(tm, __shfl_xor(tm, 1));
      tm = fmaxf(tm, __shfl_xor(tm, 2));
      tm = fmaxf(tm, __shfl_xor(tm, 4));
      tm = fmaxf(tm, __shfl_xor(tm, 8));
      float nm = fmaxf(mrun[r], tm);
      float al = expf(mrun[r] - nm);
      float p0 = expf(sacc[0][r] - nm);
      float p1 = expf(sacc[1][r] - nm);
      float p2 = expf(sacc[2][r] - nm);
      float p3 = expf(sacc[3][r] - nm);
      float rs = p0 + p1 + p2 + p3;
      rs += __shfl_xor(rs, 1);
      rs += __shfl_xor(rs, 2);
      rs += __shfl_xor(rs, 4);
      rs += __shfl_xor(rs, 8);
      srun[r] = srun[r] * al + rs;
      mrun[r] = nm;
#pragma unroll
      for (int hf = 0; hf < 4; ++hf) oacc[hf][r] *= al;
      int prow = w * 16 + lg * 4 + r;
      ushort_t ph, pm;
      splitf(p0, ph, pm); Phs[prow][0 * 16 + l15] = ph; Pms[prow][0 * 16 + l15] = pm;
      splitf(p1, ph, pm); Phs[prow][1 * 16 + l15] = ph; Pms[prow][1 * 16 + l15] = pm;
      splitf(p2, ph, pm); Phs[prow][2 * 16 + l15] = ph; Pms[prow][2 * 16 + l15] = pm;
      splitf(p3, ph, pm); Phs[prow][3 * 16 + l15] = ph; Pms[prow][3 * 16 + l15] = pm;
    }
    __syncthreads();
#pragma unroll
    for (int kg = 0; kg < 2; ++kg) {
      frag8 pf = *(const frag8*)(&Phs[w * 16 + l15][kg * 32 + (lg << 3)]);
      frag8 pf2 = *(const frag8*)(&Pms[w * 16 + l15][kg * 32 + (lg << 3)]);
#pragma unroll
      for (int hf = 0; hf < 4; ++hf) {
        frag8 vf = *(const frag8*)(&Vhs[hf * 16 + l15][kg * 32 + (lg << 3)]);
        frag8 vf2 = *(const frag8*)(&Vms[hf * 16 + l15][kg * 32 + (lg << 3)]);
        oacc[hf] = __builtin_amdgcn_mfma_f32_16x16x32_bf16(pf, vf, oacc[hf], 0, 0, 0);
        oacc[hf] = __builtin_amdgcn_mfma_f32_16x16x32_bf16(pf, vf2, oacc[hf], 0, 0, 0);
        oacc[hf] = __builtin_amdgcn_mfma_f32_16x16x32_bf16(pf2, vf, oacc[hf], 0, 0, 0);
      }
    }
  }
#pragma unroll
  for (int hf = 0; hf < 4; ++hf)
#pragma unroll
    for (int r = 0; r < 4; ++r) {
      float val = oacc[hf][r] / srun[r];
      size_t off = base + (size_t)(qt * 64 + w * 16 + lg * 4 + r) * 1024 + hf * 16 + l15;
      ushort_t h, m;
      splitf(val, h, m);
      oh[off] = h;
      om[off] = m;
    }
}

// ---------------- 4x4 pooling + mask ----------------
__global__ __launch_bounds__(256) void k_pool(const float* __restrict__ x,
                                              const int* __restrict__ pos,
                                              float* __restrict__ out,
                                              float* __restrict__ maskout) {
  __shared__ int smax[4];
  __shared__ int kidx_s[1024];
  const int blk = blockIdx.x;
  const int b = blk >> 6, oidx = blk & 63;
  const int tid = threadIdx.x;
  int mx = 0;
  for (int l = tid; l < 1024; l += 256) {
    int p0 = pos[((size_t)b * 1024 + l) * 2];
    mx = max(mx, p0 > 0 ? p0 : 0);
  }
  for (int m = 1; m < 64; m <<= 1) mx = max(mx, __shfl_xor(mx, m));
  if ((tid & 63) == 0) smax[tid >> 6] = mx;
  __syncthreads();
  int maxx = max(max(smax[0], smax[1]), max(smax[2], smax[3])) + 1;
  int mk = maxx >> 2;
  for (int l = tid; l < 1024; l += 256) {
    int p0 = pos[((size_t)b * 1024 + l) * 2];
    int p1 = pos[((size_t)b * 1024 + l) * 2 + 1];
    int c0 = p0 > 0 ? p0 : 0, c1 = p1 > 0 ? p1 : 0;
    int pad = (p0 == -1 && p1 == -1) ? 1 : 0;
    kidx_s[l] = ((c0 >> 2) + mk * (c1 >> 2)) | (pad << 16);
  }
  __syncthreads();
  float ax = 0.f, ay = 0.f, az = 0.f, aw = 0.f;
  int cnt = 0;
  for (int l = 0; l < 1024; ++l) {
    int ki = kidx_s[l];
    if ((ki & 0xffff) == oidx) {
      cnt++;
      if (!(ki >> 16)) {
        float4 xv = ((const float4*)(x + ((size_t)b * 1024 + l) * 1024))[tid];
        ax += xv.x; ay += xv.y; az += xv.z; aw += xv.w;
      }
    }
  }
  float4 res;
  res.x = ax * 2.0f; res.y = ay * 2.0f; res.z = az * 2.0f; res.w = aw * 2.0f;
  ((float4*)(out + ((size_t)b * 64 + oidx) * 1024))[tid] = res;
  if (tid == 0) maskout[b * 64 + oidx] = (cnt > 0) ? 1.0f : 0.0f;
}

// ---------------- host launch ----------------
extern "C" void kernel_launch(void* const* d_in, const int* in_sizes, int n_in,
                              void* d_out, int out_size, void* d_ws, size_t ws_size,
                              hipStream_t stream) {
  const float* pix = (const float*)d_in[0];
  const int* pos = (const int*)d_in[1];
  const float* Win = (const float*)d_in[2];
  const float* ptab = (const float*)d_in[3];
  const float* Wq = (const float*)d_in[4];
  const float* Wk = (const float*)d_in[5];
  const float* Wv = (const float*)d_in[6];
  const float* Wo = (const float*)d_in[7];
  const float* qn = (const float*)d_in[8];
  const float* kn = (const float*)d_in[9];
  const float* pre_attn = (const float*)d_in[10];
  const float* post_attn = (const float*)d_in[11];
  const float* pre_ffw = (const float*)d_in[12];
  const float* post_ffw = (const float*)d_in[13];
  const float* Wg = (const float*)d_in[14];
  const float* Wu = (const float*)d_in[15];
  const float* Wd = (const float*)d_in[16];

  char* w = (char*)d_ws;
  float* x = (float*)w;        w += 16777216;
  float* tmp = (float*)w;      w += 16777216;
  ushort_t* hh = (ushort_t*)w; w += 8388608;
  ushort_t* hm = (ushort_t*)w; w += 8388608;
  char* regB = w;  // 128 MiB overlapped region
  ushort_t* qh_ = (ushort_t*)(regB + 0);
  ushort_t* qm_ = (ushort_t*)(regB + 8388608);
  ushort_t* kh_ = (ushort_t*)(regB + 16777216);
  ushort_t* km_ = (ushort_t*)(regB + 25165824);
  ushort_t* vh_ = (ushort_t*)(regB + 33554432);
  ushort_t* vm_ = (ushort_t*)(regB + 41943040);
  ushort_t* aoh = (ushort_t*)(regB + 50331648);
  ushort_t* aom = (ushort_t*)(regB + 58720256);
  ushort_t* wat_h = (ushort_t*)(regB + 67108864);
  ushort_t* wat_m = (ushort_t*)(regB + 75497472);
  // O-proj partials: qh_..vm_ region (0..50MB) is dead after k_attn_s
  float* po1 = (float*)(regB + 0);
  float* po2 = (float*)(regB + 16777216);
  float* po3 = (float*)(regB + 33554432);
  ushort_t* mh = (ushort_t*)(regB + 0);
  ushort_t* mm = (ushort_t*)(regB + 33554432);
  ushort_t* wgu_h = (ushort_t*)(regB + 67108864);
  ushort_t* wgu_m = (ushort_t*)(regB + 83886080);
  ushort_t* wd_h = (ushort_t*)(regB + 100663296);
  ushort_t* wd_m = (ushort_t*)(regB + 109051904);
  // down-proj partials: wgu (67..100MB) dead after k_ffw_up; hh/hm dead after k_ffw_up
  float* pd1 = (float*)(regB + 67108864);
  float* pd2 = (float*)(regB + 83886080);
  float* pd3 = (float*)hh;  // ws+32MB..48MB (hh+hm contiguous 16MB)
  ushort_t* pixh = (ushort_t*)(regB + 0);
  ushort_t* pixm = (ushort_t*)(regB + 6291456);
  ushort_t* win_h = (ushort_t*)(regB + 67108864);
  ushort_t* win_m = (ushort_t*)(regB + 71303168);

  dim3 blk(256);
  k_splitpix<<<3072, blk, 0, stream>>>(pix, pixh, pixm, 786432);
  k_posemb<<<4096, blk, 0, stream>>>(pos, ptab, x);
  k_wsplit4<<<dim3(16, 12, 1), blk, 0, stream>>>(Win, Win, Win, Win, win_h, win_m, 768, 1024);
  k_gemm_s<EPI_ADDF32><<<256, blk, 0, stream>>>(pixh, pixm, win_h, win_m, x, nullptr,
                                                768, 1024, 24);

  for (int i = 0; i < 6; ++i) {
    const float* wq = Wq + (size_t)i * 1048576;
    const float* wk = Wk + (size_t)i * 1048576;
    const float* wv = Wv + (size_t)i * 1048576;
    const float* wo = Wo + (size_t)i * 1048576;
    const float* wg = Wg + (size_t)i * 4194304;
    const float* wu = Wu + (size_t)i * 4194304;
    const float* wd = Wd + (size_t)i * 4194304;

    k_rmsnorm_s<<<4096, blk, 0, stream>>>(x, pre_attn + i * 1024, hh, hm);
    k_wsplit4<<<dim3(16, 16, 4), blk, 0, stream>>>(wq, wk, wv, wo, wat_h, wat_m, 1024, 1024);
    k_qkv<<<768, blk, 0, stream>>>(hh, hm, wat_h, wat_m, qn + i * 64, kn + i * 64, pos,
                                   qh_, qm_, kh_, km_, vh_, vm_);
    k_attn_s<<<1024, blk, 0, stream>>>(qh_, qm_, kh_, km_, vh_, vm_, aoh, aom);
    k_gemm_s8<<<512, blk, 0, stream>>>(aoh, aom, wat_h + 3145728, wat_m + 3145728,
                                       tmp, po1, po2, po3, 1024, 1024, 8);
    k_addrms4<<<4096, blk, 0, stream>>>(x, tmp, po1, po2, po3, post_attn + i * 1024);

    k_rmsnorm_s<<<4096, blk, 0, stream>>>(x, pre_ffw + i * 1024, hh, hm);
    k_wsplit4<<<dim3(64, 16, 2), blk, 0, stream>>>(wg, wu, wg, wu, wgu_h, wgu_m, 1024, 4096);
    k_wsplit4<<<dim3(16, 64, 1), blk, 0, stream>>>(wd, wd, wd, wd, wd_h, wd_m, 4096, 1024);
    k_ffw_up<<<1024, blk, 0, stream>>>(hh, hm, wgu_h, wgu_m, wgu_h + 4194304, wgu_m + 4194304,
                                       mh, mm);
    k_gemm_s8<<<512, blk, 0, stream>>>(mh, mm, wd_h, wd_m, tmp, pd1, pd2, pd3,
                                       4096, 1024, 32);
    k_addrms4<<<4096, blk, 0, stream>>>(x, tmp, pd1, pd2, pd3, post_ffw + i * 1024);
  }

  k_pool<<<256, blk, 0, stream>>>(x, pos, (float*)d_out, (float*)d_out + 262144);
}

// Round 14
// 4621.667 us; speedup vs baseline: 1.1154x; 1.0297x over previous
//
#include <hip/hip_runtime.h>
#include <stdint.h>

typedef unsigned short ushort_t;
using frag8 = __attribute__((ext_vector_type(8))) short;
using f32x4 = __attribute__((ext_vector_type(4))) float;

static __device__ __forceinline__ unsigned short f2bf(float f) {
  union { float f; unsigned u; } v; v.f = f;
  unsigned r = v.u + 0x7fffu + ((v.u >> 16) & 1u);
  return (unsigned short)(r >> 16);
}
static __device__ __forceinline__ float bf2f(unsigned short b) {
  union { unsigned u; float f; } v; v.u = ((unsigned)b) << 16; return v.f;
}
static __device__ __forceinline__ void splitf(float v, ushort_t& h, ushort_t& m) {
  h = f2bf(v);
  m = f2bf(v - bf2f(h));
}

// ---------------- pix split ----------------
__global__ __launch_bounds__(256) void k_splitpix(const float* __restrict__ pix,
                                                  ushort_t* __restrict__ oh,
                                                  ushort_t* __restrict__ om, int n4) {
  int i = blockIdx.x * 256 + threadIdx.x;
  if (i >= n4) return;
  float4 v = ((const float4*)pix)[i];
  ushort4 h, m;
  splitf(2.f * (v.x - 0.5f), h.x, m.x);
  splitf(2.f * (v.y - 0.5f), h.y, m.y);
  splitf(2.f * (v.z - 0.5f), h.z, m.z);
  splitf(2.f * (v.w - 0.5f), h.w, m.w);
  ((ushort4*)oh)[i] = h;
  ((ushort4*)om)[i] = m;
}

// ---------------- transpose-split: f32 [K][N] -> bf16 hi/mid [N][K] ----------------
__global__ __launch_bounds__(256) void k_wsplit4(const float* __restrict__ B0,
                                                 const float* __restrict__ B1,
                                                 const float* __restrict__ B2,
                                                 const float* __restrict__ B3,
                                                 ushort_t* __restrict__ th,
                                                 ushort_t* __restrict__ tm,
                                                 int K, int N) {
  __shared__ float ts[64][65];
  const int z = blockIdx.z;
  const float* B = (z == 0) ? B0 : (z == 1) ? B1 : (z == 2) ? B2 : B3;
  th += (size_t)z * K * N;
  tm += (size_t)z * K * N;
  const int tid = threadIdx.x;
  const int n0 = blockIdx.x << 6, k0 = blockIdx.y << 6;
  int rr = tid >> 4, cc = (tid & 15) << 2;
#pragma unroll
  for (int j = 0; j < 4; ++j) {
    int r = rr + j * 16;
    float4 v = *(const float4*)(B + (size_t)(k0 + r) * N + n0 + cc);
    ts[r][cc] = v.x; ts[r][cc + 1] = v.y; ts[r][cc + 2] = v.z; ts[r][cc + 3] = v.w;
  }
  __syncthreads();
  int n = tid >> 2;
  int kc = (tid & 3) << 4;
  ushort_t oh[16], om[16];
#pragma unroll
  for (int j = 0; j < 16; ++j) splitf(ts[kc + j][n], oh[j], om[j]);
  ushort_t* ph = th + (size_t)(n0 + n) * K + k0 + kc;
  ushort_t* pm = tm + (size_t)(n0 + n) * K + k0 + kc;
  *(uint4*)(ph) = *(uint4*)(oh);
  *(uint4*)(ph + 8) = *(uint4*)(oh + 8);
  *(uint4*)(pm) = *(uint4*)(om);
  *(uint4*)(pm + 8) = *(uint4*)(om + 8);
}

// ---------------- pos-emb fill ----------------
__global__ __launch_bounds__(256) void k_posemb(const int* __restrict__ pos,
                                                const float* __restrict__ ptab,
                                                float* __restrict__ x) {
  int row = blockIdx.x, tid = threadIdx.x;
  int p0 = pos[(size_t)row * 2], p1 = pos[(size_t)row * 2 + 1];
  bool pad = (p0 == -1) && (p1 == -1);
  int px = p0 > 0 ? p0 : 0, py = p1 > 0 ? p1 : 0;
  float4 a = ((const float4*)(ptab + (size_t)px * 1024))[tid];
  float4 b = ((const float4*)(ptab + 65536 + (size_t)py * 1024))[tid];
  float4 o;
  o.x = pad ? 0.f : a.x + b.x;
  o.y = pad ? 0.f : a.y + b.y;
  o.z = pad ? 0.f : a.z + b.z;
  o.w = pad ? 0.f : a.w + b.w;
  ((float4*)(x + (size_t)row * 1024))[tid] = o;
}

// ---------------- RMSNorm D=1024: f32 -> hi/mid bf16 ----------------
__global__ __launch_bounds__(256) void k_rmsnorm_s(const float* __restrict__ x,
                                                   const float* __restrict__ scale,
                                                   ushort_t* __restrict__ oh,
                                                   ushort_t* __restrict__ om) {
  __shared__ float wsum[4];
  int row = blockIdx.x, tid = threadIdx.x;
  float4 v = ((const float4*)(x + (size_t)row * 1024))[tid];
  float ss = v.x * v.x + v.y * v.y + v.z * v.z + v.w * v.w;
  for (int m = 1; m < 64; m <<= 1) ss += __shfl_xor(ss, m);
  if ((tid & 63) == 0) wsum[tid >> 6] = ss;
  __syncthreads();
  float tot = wsum[0] + wsum[1] + wsum[2] + wsum[3];
  float r = rsqrtf(tot * (1.f / 1024.f) + 1e-6f);
  float4 sc = ((const float4*)scale)[tid];
  ushort4 h, m;
  splitf(v.x * r * sc.x, h.x, m.x);
  splitf(v.y * r * sc.y, h.y, m.y);
  splitf(v.z * r * sc.z, h.z, m.z);
  splitf(v.w * r * sc.w, h.w, m.w);
  ((ushort4*)(oh + (size_t)row * 1024))[tid] = h;
  ((ushort4*)(om + (size_t)row * 1024))[tid] = m;
}

// ---------------- x += RMSNorm(t1+t2)*scale (f32), no norm output ----------------
__global__ __launch_bounds__(256) void k_addrms32(float* __restrict__ x,
                                                  const float* __restrict__ t1,
                                                  const float* __restrict__ t2,
                                                  const float* __restrict__ scale) {
  __shared__ float wsum[4];
  int row = blockIdx.x, tid = threadIdx.x;
  float4 v = ((const float4*)(t1 + (size_t)row * 1024))[tid];
  float4 v2 = ((const float4*)(t2 + (size_t)row * 1024))[tid];
  v.x += v2.x; v.y += v2.y; v.z += v2.z; v.w += v2.w;
  float ss = v.x * v.x + v.y * v.y + v.z * v.z + v.w * v.w;
  for (int m = 1; m < 64; m <<= 1) ss += __shfl_xor(ss, m);
  if ((tid & 63) == 0) wsum[tid >> 6] = ss;
  __syncthreads();
  float tot = wsum[0] + wsum[1] + wsum[2] + wsum[3];
  float r = rsqrtf(tot * (1.f / 1024.f) + 1e-6f);
  float4 sc = ((const float4*)scale)[tid];
  float4 xv = ((const float4*)(x + (size_t)row * 1024))[tid];
  xv.x += v.x * r * sc.x;
  xv.y += v.y * r * sc.y;
  xv.z += v.z * r * sc.z;
  xv.w += v.w * r * sc.w;
  ((float4*)(x + (size_t)row * 1024))[tid] = xv;
}

// ---------------- fused: x += RMSNorm(t1+t2)*sadd; then oh/om = split(RMSNorm(x)*snorm) ----------------
__global__ __launch_bounds__(256) void k_addrms_ns(float* __restrict__ x,
                                                   const float* __restrict__ t1,
                                                   const float* __restrict__ t2,
                                                   const float* __restrict__ sadd,
                                                   const float* __restrict__ snorm,
                                                   ushort_t* __restrict__ oh,
                                                   ushort_t* __restrict__ om) {
  __shared__ float wsum[4];
  __shared__ float wsum2[4];
  int row = blockIdx.x, tid = threadIdx.x;
  float4 v = ((const float4*)(t1 + (size_t)row * 1024))[tid];
  float4 v2 = ((const float4*)(t2 + (size_t)row * 1024))[tid];
  v.x += v2.x; v.y += v2.y; v.z += v2.z; v.w += v2.w;
  float ss = v.x * v.x + v.y * v.y + v.z * v.z + v.w * v.w;
  for (int m = 1; m < 64; m <<= 1) ss += __shfl_xor(ss, m);
  if ((tid & 63) == 0) wsum[tid >> 6] = ss;
  __syncthreads();
  float tot = wsum[0] + wsum[1] + wsum[2] + wsum[3];
  float r = rsqrtf(tot * (1.f / 1024.f) + 1e-6f);
  float4 sc = ((const float4*)sadd)[tid];
  float4 xv = ((const float4*)(x + (size_t)row * 1024))[tid];
  xv.x += v.x * r * sc.x;
  xv.y += v.y * r * sc.y;
  xv.z += v.z * r * sc.z;
  xv.w += v.w * r * sc.w;
  ((float4*)(x + (size_t)row * 1024))[tid] = xv;
  // second RMS over the updated row
  float ss2 = xv.x * xv.x + xv.y * xv.y + xv.z * xv.z + xv.w * xv.w;
  for (int m = 1; m < 64; m <<= 1) ss2 += __shfl_xor(ss2, m);
  if ((tid & 63) == 0) wsum2[tid >> 6] = ss2;
  __syncthreads();
  float tot2 = wsum2[0] + wsum2[1] + wsum2[2] + wsum2[3];
  float r2 = rsqrtf(tot2 * (1.f / 1024.f) + 1e-6f);
  float4 sn = ((const float4*)snorm)[tid];
  ushort4 h, m;
  splitf(xv.x * r2 * sn.x, h.x, m.x);
  splitf(xv.y * r2 * sn.y, h.y, m.y);
  splitf(xv.z * r2 * sn.z, h.z, m.z);
  splitf(xv.w * r2 * sn.w, h.w, m.w);
  ((ushort4*)(oh + (size_t)row * 1024))[tid] = h;
  ((ushort4*)(om + (size_t)row * 1024))[tid] = m;
}

#define SWZ_COL(r, c) (((c) ^ (((r) >> 3) & 3)) << 3)

// ================= fused QKV GEMM + per-head RMS + RoPE (128x128, round-11 proven) =================
__global__ __launch_bounds__(256) void k_qkv(const ushort_t* __restrict__ Ah,
                                             const ushort_t* __restrict__ Am,
                                             const ushort_t* __restrict__ WT_h,
                                             const ushort_t* __restrict__ WT_m,
                                             const float* __restrict__ qn,
                                             const float* __restrict__ kn,
                                             const int* __restrict__ pos,
                                             ushort_t* __restrict__ qh, ushort_t* __restrict__ qm,
                                             ushort_t* __restrict__ kh, ushort_t* __restrict__ km,
                                             ushort_t* __restrict__ vh, ushort_t* __restrict__ vm) {
  __shared__ __align__(16) ushort_t Ash[128][40];
  __shared__ __align__(16) ushort_t Asl[128][40];
  __shared__ __align__(16) ushort_t Bsh[128][40];
  __shared__ __align__(16) ushort_t Bsl[128][40];
  const int tid = threadIdx.x;
  const int bid = blockIdx.x;
  const int xcd = bid & 7, lo = bid >> 3;
  const int ntl = lo % 3, mt = lo / 3;
  const int nt = xcd * 3 + ntl;
  const int mat = nt >> 3;
  const int n0 = (nt & 7) << 7;
  const int m0 = mt << 7;
  const ushort_t* Bh = WT_h + (size_t)mat * 1048576;
  const ushort_t* Bm = WT_m + (size_t)mat * 1048576;

  const int lane = tid & 63;
  const int wm = ((tid >> 7) & 1) * 64;
  const int wn = ((tid >> 6) & 1) * 64;
  const int l15 = lane & 15, lg = lane >> 4;
  const int srow = tid >> 1, scol = (tid & 1) << 4;
  const int cb = (tid & 1) << 1;
  const int wc0 = SWZ_COL(srow, cb), wc1 = SWZ_COL(srow, cb + 1);
  f32x4 acc[4][4] = {};

  for (int k0 = 0; k0 < 1024; k0 += 32) {
    const ushort_t* gah = Ah + (size_t)(m0 + srow) * 1024 + k0 + scol;
    const ushort_t* gam = Am + (size_t)(m0 + srow) * 1024 + k0 + scol;
    const ushort_t* gbh = Bh + (size_t)(n0 + srow) * 1024 + k0 + scol;
    const ushort_t* gbm = Bm + (size_t)(n0 + srow) * 1024 + k0 + scol;
    uint4 a0 = *(const uint4*)gah, a1 = *(const uint4*)(gah + 8);
    uint4 a2 = *(const uint4*)gam, a3 = *(const uint4*)(gam + 8);
    uint4 b0 = *(const uint4*)gbh, b1 = *(const uint4*)(gbh + 8);
    uint4 b2 = *(const uint4*)gbm, b3 = *(const uint4*)(gbm + 8);
    *(uint4*)(&Ash[srow][wc0]) = a0;
    *(uint4*)(&Ash[srow][wc1]) = a1;
    *(uint4*)(&Asl[srow][wc0]) = a2;
    *(uint4*)(&Asl[srow][wc1]) = a3;
    *(uint4*)(&Bsh[srow][wc0]) = b0;
    *(uint4*)(&Bsh[srow][wc1]) = b1;
    *(uint4*)(&Bsl[srow][wc0]) = b2;
    *(uint4*)(&Bsl[srow][wc1]) = b3;
    __syncthreads();
    frag8 ah[4], al[4], bh[4], bl[4];
#pragma unroll
    for (int i = 0; i < 4; ++i) {
      int rA = wm + i * 16 + l15, rB = wn + i * 16 + l15;
      int cA = SWZ_COL(rA, lg), cB = SWZ_COL(rB, lg);
      ah[i] = *(const frag8*)(&Ash[rA][cA]);
      al[i] = *(const frag8*)(&Asl[rA][cA]);
      bh[i] = *(const frag8*)(&Bsh[rB][cB]);
      bl[i] = *(const frag8*)(&Bsl[rB][cB]);
    }
#pragma unroll
    for (int mi = 0; mi < 4; ++mi)
#pragma unroll
      for (int ni = 0; ni < 4; ++ni) {
        acc[mi][ni] = __builtin_amdgcn_mfma_f32_16x16x32_bf16(ah[mi], bh[ni], acc[mi][ni], 0, 0, 0);
        acc[mi][ni] = __builtin_amdgcn_mfma_f32_16x16x32_bf16(ah[mi], bl[ni], acc[mi][ni], 0, 0, 0);
        acc[mi][ni] = __builtin_amdgcn_mfma_f32_16x16x32_bf16(al[mi], bh[ni], acc[mi][ni], 0, 0, 0);
      }
    __syncthreads();
  }

  const float* scale = (mat == 0) ? qn : (mat == 1 ? kn : nullptr);
  ushort_t* outh = (mat == 0) ? qh : (mat == 1 ? kh : vh);
  ushort_t* outm = (mat == 0) ? qm : (mat == 1 ? km : vm);
  const float inv = powf(10000.f, -(float)l15 * (1.f / 16.f));
#pragma unroll
  for (int mi = 0; mi < 4; ++mi) {
#pragma unroll
    for (int rr = 0; rr < 4; ++rr) {
      float ss = 0.f;
#pragma unroll
      for (int ni = 0; ni < 4; ++ni) { float v = acc[mi][ni][rr]; ss += v * v; }
      ss += __shfl_xor(ss, 1);
      ss += __shfl_xor(ss, 2);
      ss += __shfl_xor(ss, 4);
      ss += __shfl_xor(ss, 8);
      float rs = rsqrtf(ss * (1.f / 64.f) + 1e-6f);
      int row = m0 + wm + mi * 16 + (lg << 2) + rr;
      float nv[4];
#pragma unroll
      for (int ni = 0; ni < 4; ++ni) {
        float sc = scale ? scale[ni * 16 + l15] : 1.f;
        nv[ni] = acc[mi][ni][rr] * rs * sc;
      }
      if (mat < 2) {
        int p0 = pos[(size_t)row * 2], p1 = pos[(size_t)row * 2 + 1];
        p0 = p0 > 0 ? p0 : 0;
        p1 = p1 > 0 ? p1 : 0;
        float a0 = (float)p0 * inv, a1 = (float)p1 * inv;
        float c0 = cosf(a0), s0 = sinf(a0);
        float c1 = cosf(a1), s1 = sinf(a1);
        float t0 = nv[0] * c0 - nv[1] * s0;
        float t1 = nv[1] * c0 + nv[0] * s0;
        float t2 = nv[2] * c1 - nv[3] * s1;
        float t3 = nv[3] * c1 + nv[2] * s1;
        nv[0] = t0; nv[1] = t1; nv[2] = t2; nv[3] = t3;
      }
#pragma unroll
      for (int ni = 0; ni < 4; ++ni) {
        ushort_t h, m;
        splitf(nv[ni], h, m);
        size_t idx = (size_t)row * 1024 + n0 + wn + ni * 16 + l15;
        outh[idx] = h;
        outm[idx] = m;
      }
    }
  }
}

// ================= fused FFW up (round-11 proven, unchanged) =================
__global__ __launch_bounds__(256) void k_ffw_up(const ushort_t* __restrict__ Ah,
                                                const ushort_t* __restrict__ Am,
                                                const ushort_t* __restrict__ Gh,
                                                const ushort_t* __restrict__ Gm,
                                                const ushort_t* __restrict__ Uh,
                                                const ushort_t* __restrict__ Um,
                                                ushort_t* __restrict__ Oh,
                                                ushort_t* __restrict__ Om) {
  __shared__ __align__(16) ushort_t Ash[128][40];
  __shared__ __align__(16) ushort_t Asl[128][40];
  __shared__ __align__(16) ushort_t Bgh[128][40];
  __shared__ __align__(16) ushort_t Bgl[128][40];
  __shared__ __align__(16) ushort_t Buh[128][40];
  __shared__ __align__(16) ushort_t Bul[128][40];
  const int tid = threadIdx.x;
  const int bid = blockIdx.x;
  const int xcd = bid & 7, lo = bid >> 3;
  const int nt = xcd * 4 + (lo & 3);
  const int mt = lo >> 2;
  const int m0 = mt << 7, n0 = nt << 7;
  const int lane = tid & 63;
  const int wm = ((tid >> 7) & 1) * 64;
  const int wn = ((tid >> 6) & 1) * 64;
  const int l15 = lane & 15, lg = lane >> 4;
  const int srow = tid >> 1, scol = (tid & 1) << 4;
  const int cb = (tid & 1) << 1;
  const int wc0 = SWZ_COL(srow, cb), wc1 = SWZ_COL(srow, cb + 1);
  f32x4 ag[4][4] = {};
  f32x4 au[4][4] = {};

  for (int k0 = 0; k0 < 1024; k0 += 32) {
    const ushort_t* gah = Ah + (size_t)(m0 + srow) * 1024 + k0 + scol;
    const ushort_t* gam = Am + (size_t)(m0 + srow) * 1024 + k0 + scol;
    const ushort_t* ggh = Gh + (size_t)(n0 + srow) * 1024 + k0 + scol;
    const ushort_t* ggm = Gm + (size_t)(n0 + srow) * 1024 + k0 + scol;
    const ushort_t* guh = Uh + (size_t)(n0 + srow) * 1024 + k0 + scol;
    const ushort_t* gum = Um + (size_t)(n0 + srow) * 1024 + k0 + scol;
    uint4 a0 = *(const uint4*)gah, a1 = *(const uint4*)(gah + 8);
    uint4 a2 = *(const uint4*)gam, a3 = *(const uint4*)(gam + 8);
    uint4 g0 = *(const uint4*)ggh, g1 = *(const uint4*)(ggh + 8);
    uint4 g2 = *(const uint4*)ggm, g3 = *(const uint4*)(ggm + 8);
    uint4 u0 = *(const uint4*)guh, u1 = *(const uint4*)(guh + 8);
    uint4 u2 = *(const uint4*)gum, u3 = *(const uint4*)(gum + 8);
    *(uint4*)(&Ash[srow][wc0]) = a0;
    *(uint4*)(&Ash[srow][wc1]) = a1;
    *(uint4*)(&Asl[srow][wc0]) = a2;
    *(uint4*)(&Asl[srow][wc1]) = a3;
    *(uint4*)(&Bgh[srow][wc0]) = g0;
    *(uint4*)(&Bgh[srow][wc1]) = g1;
    *(uint4*)(&Bgl[srow][wc0]) = g2;
    *(uint4*)(&Bgl[srow][wc1]) = g3;
    *(uint4*)(&Buh[srow][wc0]) = u0;
    *(uint4*)(&Buh[srow][wc1]) = u1;
    *(uint4*)(&Bul[srow][wc0]) = u2;
    *(uint4*)(&Bul[srow][wc1]) = u3;
    __syncthreads();
    frag8 ah[4], al[4];
#pragma unroll
    for (int i = 0; i < 4; ++i) {
      int rA = wm + i * 16 + l15;
      int cA = SWZ_COL(rA, lg);
      ah[i] = *(const frag8*)(&Ash[rA][cA]);
      al[i] = *(const frag8*)(&Asl[rA][cA]);
    }
#pragma unroll
    for (int ni = 0; ni < 4; ++ni) {
      int rB = wn + ni * 16 + l15;
      int cB = SWZ_COL(rB, lg);
      frag8 bgh = *(const frag8*)(&Bgh[rB][cB]);
      frag8 bgl = *(const frag8*)(&Bgl[rB][cB]);
      frag8 buh = *(const frag8*)(&Buh[rB][cB]);
      frag8 bul = *(const frag8*)(&Bul[rB][cB]);
#pragma unroll
      for (int mi = 0; mi < 4; ++mi) {
        ag[mi][ni] = __builtin_amdgcn_mfma_f32_16x16x32_bf16(ah[mi], bgh, ag[mi][ni], 0, 0, 0);
        ag[mi][ni] = __builtin_amdgcn_mfma_f32_16x16x32_bf16(ah[mi], bgl, ag[mi][ni], 0, 0, 0);
        ag[mi][ni] = __builtin_amdgcn_mfma_f32_16x16x32_bf16(al[mi], bgh, ag[mi][ni], 0, 0, 0);
        au[mi][ni] = __builtin_amdgcn_mfma_f32_16x16x32_bf16(ah[mi], buh, au[mi][ni], 0, 0, 0);
        au[mi][ni] = __builtin_amdgcn_mfma_f32_16x16x32_bf16(ah[mi], bul, au[mi][ni], 0, 0, 0);
        au[mi][ni] = __builtin_amdgcn_mfma_f32_16x16x32_bf16(al[mi], buh, au[mi][ni], 0, 0, 0);
      }
    }
    __syncthreads();
  }

#pragma unroll
  for (int mi = 0; mi < 4; ++mi) {
#pragma unroll
    for (int ni = 0; ni < 4; ++ni) {
#pragma unroll
      for (int r = 0; r < 4; ++r) {
        float vg = ag[mi][ni][r];
        float x3 = vg * vg * vg;
        float gel = 0.5f * vg * (1.f + tanhf(0.7978845608028654f * (vg + 0.044715f * x3)));
        float v2 = gel * au[mi][ni][r];
        int gr = m0 + wm + mi * 16 + (lg << 2) + r;
        int gc = n0 + wn + ni * 16 + l15;
        size_t idx = (size_t)gr * 4096 + gc;
        ushort_t h, m;
        splitf(v2, h, m);
        Oh[idx] = h;
        Om[idx] = m;
      }
    }
  }
}

// ---------------- mi=4 split GEMM, K-split capable (round-11 proven) ----------------
enum { EPI_F32 = 0, EPI_ADDF32 = 1 };

template <int EPI>
__global__ __launch_bounds__(256) void k_gemm_s(const ushort_t* __restrict__ Ah,
                                                const ushort_t* __restrict__ Am,
                                                const ushort_t* __restrict__ Bh,
                                                const ushort_t* __restrict__ Bm,
                                                float* C0, float* C1,
                                                int K, int N, int ksteps) {
  __shared__ __align__(16) ushort_t Ash[128][40];
  __shared__ __align__(16) ushort_t Asl[128][40];
  __shared__ __align__(16) ushort_t Bsh[128][40];
  __shared__ __align__(16) ushort_t Bsl[128][40];
  const int tid = threadIdx.x;
  const int bid = blockIdx.x;
  const int half = bid >> 8;
  const int inner = bid & 255;
  float* Cf = half ? C1 : C0;
  const int kbase = half * ksteps * 32;
  const int xcd = inner & 7, lo = inner >> 3;
  const int mt = xcd * 4 + (lo >> 3);
  const int nt = lo & 7;
  const int m0 = mt << 7, n0 = nt << 7;
  const int lane = tid & 63;
  const int wm = ((tid >> 7) & 1) * 64;
  const int wn = ((tid >> 6) & 1) * 64;
  const int l15 = lane & 15, lg = lane >> 4;
  const int srow = tid >> 1, scol = (tid & 1) << 4;
  const int cb = (tid & 1) << 1;
  const int wc0 = SWZ_COL(srow, cb), wc1 = SWZ_COL(srow, cb + 1);
  f32x4 acc[4][4] = {};

  for (int ks = 0; ks < ksteps; ++ks) {
    const int k0 = kbase + ks * 32;
    const ushort_t* gah = Ah + (size_t)(m0 + srow) * K + k0 + scol;
    const ushort_t* gam = Am + (size_t)(m0 + srow) * K + k0 + scol;
    const ushort_t* gbh = Bh + (size_t)(n0 + srow) * K + k0 + scol;
    const ushort_t* gbm = Bm + (size_t)(n0 + srow) * K + k0 + scol;
    uint4 a0 = *(const uint4*)gah, a1 = *(const uint4*)(gah + 8);
    uint4 a2 = *(const uint4*)gam, a3 = *(const uint4*)(gam + 8);
    uint4 b0 = *(const uint4*)gbh, b1 = *(const uint4*)(gbh + 8);
    uint4 b2 = *(const uint4*)gbm, b3 = *(const uint4*)(gbm + 8);
    *(uint4*)(&Ash[srow][wc0]) = a0;
    *(uint4*)(&Ash[srow][wc1]) = a1;
    *(uint4*)(&Asl[srow][wc0]) = a2;
    *(uint4*)(&Asl[srow][wc1]) = a3;
    *(uint4*)(&Bsh[srow][wc0]) = b0;
    *(uint4*)(&Bsh[srow][wc1]) = b1;
    *(uint4*)(&Bsl[srow][wc0]) = b2;
    *(uint4*)(&Bsl[srow][wc1]) = b3;
    __syncthreads();
    frag8 ah[4], al[4], bh[4], bl[4];
#pragma unroll
    for (int i = 0; i < 4; ++i) {
      int rA = wm + i * 16 + l15, rB = wn + i * 16 + l15;
      int cA = SWZ_COL(rA, lg), cB = SWZ_COL(rB, lg);
      ah[i] = *(const frag8*)(&Ash[rA][cA]);
      al[i] = *(const frag8*)(&Asl[rA][cA]);
      bh[i] = *(const frag8*)(&Bsh[rB][cB]);
      bl[i] = *(const frag8*)(&Bsl[rB][cB]);
    }
#pragma unroll
    for (int mi = 0; mi < 4; ++mi)
#pragma unroll
      for (int ni = 0; ni < 4; ++ni) {
        acc[mi][ni] = __builtin_amdgcn_mfma_f32_16x16x32_bf16(ah[mi], bh[ni], acc[mi][ni], 0, 0, 0);
        acc[mi][ni] = __builtin_amdgcn_mfma_f32_16x16x32_bf16(ah[mi], bl[ni], acc[mi][ni], 0, 0, 0);
        acc[mi][ni] = __builtin_amdgcn_mfma_f32_16x16x32_bf16(al[mi], bh[ni], acc[mi][ni], 0, 0, 0);
      }
    __syncthreads();
  }

#pragma unroll
  for (int mi = 0; mi < 4; ++mi) {
#pragma unroll
    for (int ni = 0; ni < 4; ++ni) {
#pragma unroll
      for (int r = 0; r < 4; ++r) {
        float val = acc[mi][ni][r];
        int gr = m0 + wm + mi * 16 + (lg << 2) + r;
        int gc = n0 + wn + ni * 16 + l15;
        size_t idx = (size_t)gr * N + gc;
        if (EPI == EPI_F32) Cf[idx] = val;
        else Cf[idx] += val;
      }
    }
  }
}

// ---------------- split-bf16 MFMA flash attention (unchanged, verified) ----------------
__global__ __launch_bounds__(256) void k_attn_s(const ushort_t* __restrict__ qh,
                                                const ushort_t* __restrict__ qm,
                                                const ushort_t* __restrict__ kh,
                                                const ushort_t* __restrict__ km,
                                                const ushort_t* __restrict__ vh,
                                                const ushort_t* __restrict__ vm,
                                                ushort_t* __restrict__ oh,
                                                ushort_t* __restrict__ om) {
  __shared__ __align__(16) ushort_t Khs[64][72];
  __shared__ __align__(16) ushort_t Kms[64][72];
  __shared__ __align__(16) ushort_t Vhs[64][72];
  __shared__ __align__(16) ushort_t Vms[64][72];
  __shared__ __align__(16) ushort_t Phs[64][72];
  __shared__ __align__(16) ushort_t Pms[64][72];
  const int tid = threadIdx.x;
  const int bid = blockIdx.x;
  const int xcd = bid & 7, lo = bid >> 3;
  const int bh_ = xcd * 8 + (lo >> 4);
  const int qt = lo & 15;
  const int b = bh_ >> 4, n = bh_ & 15;
  const size_t base = (size_t)b * 1048576 + (size_t)n * 64;
  const int lane = tid & 63, w = tid >> 6;
  const int l15 = lane & 15, lg = lane >> 4;

  {
    int row = tid >> 2, cg = (tid & 3) << 4;
    const uint4* sh = (const uint4*)(qh + base + (size_t)(qt * 64 + row) * 1024 + cg);
    const uint4* sm = (const uint4*)(qm + base + (size_t)(qt * 64 + row) * 1024 + cg);
    uint4 h0 = sh[0], h1 = sh[1], m0v = sm[0], m1v = sm[1];
    *(uint4*)(&Khs[row][cg]) = h0;
    *(uint4*)(&Khs[row][cg + 8]) = h1;
    *(uint4*)(&Kms[row][cg]) = m0v;
    *(uint4*)(&Kms[row][cg + 8]) = m1v;
  }
  __syncthreads();
  frag8 qh0 = *(const frag8*)(&Khs[w * 16 + l15][lg << 3]);
  frag8 qh1 = *(const frag8*)(&Khs[w * 16 + l15][32 + (lg << 3)]);
  frag8 qm0 = *(const frag8*)(&Kms[w * 16 + l15][lg << 3]);
  frag8 qm1 = *(const frag8*)(&Kms[w * 16 + l15][32 + (lg << 3)]);

  f32x4 oacc[4] = {};
  float mrun[4], srun[4];
#pragma unroll
  for (int r = 0; r < 4; ++r) { mrun[r] = -3.0e38f; srun[r] = 0.f; }

  for (int t = 0; t < 16; ++t) {
    __syncthreads();
    {
      int row = tid >> 2, cg = (tid & 3) << 4;
      const uint4* sh = (const uint4*)(kh + base + (size_t)(t * 64 + row) * 1024 + cg);
      const uint4* sm = (const uint4*)(km + base + (size_t)(t * 64 + row) * 1024 + cg);
      uint4 h0 = sh[0], h1 = sh[1], m0v = sm[0], m1v = sm[1];
      *(uint4*)(&Khs[row][cg]) = h0;
      *(uint4*)(&Khs[row][cg + 8]) = h1;
      *(uint4*)(&Kms[row][cg]) = m0v;
      *(uint4*)(&Kms[row][cg + 8]) = m1v;
    }
    {
      int hcol = tid & 63, kg = tid >> 6;
      ushort_t th[16], tm_[16];
#pragma unroll
      for (int j = 0; j < 16; ++j) {
        size_t off = base + (size_t)(t * 64 + kg * 16 + j) * 1024 + hcol;
        th[j] = vh[off];
        tm_[j] = vm[off];
      }
#pragma unroll
      for (int g = 0; g < 4; ++g) {
        ushort4 wv, wv2;
        wv.x = th[g * 4]; wv.y = th[g * 4 + 1]; wv.z = th[g * 4 + 2]; wv.w = th[g * 4 + 3];
        wv2.x = tm_[g * 4]; wv2.y = tm_[g * 4 + 1]; wv2.z = tm_[g * 4 + 2]; wv2.w = tm_[g * 4 + 3];
        *(ushort4*)(&Vhs[hcol][kg * 16 + g * 4]) = wv;
        *(ushort4*)(&Vms[hcol][kg * 16 + g * 4]) = wv2;
      }
    }
    __syncthreads();

    f32x4 sacc[4] = {};
#pragma unroll
    for (int nf = 0; nf < 4; ++nf) {
      frag8 kh0 = *(const frag8*)(&Khs[nf * 16 + l15][lg << 3]);
      frag8 kh1 = *(const frag8*)(&Khs[nf * 16 + l15][32 + (lg << 3)]);
      frag8 km0 = *(const frag8*)(&Kms[nf * 16 + l15][lg << 3]);
      frag8 km1 = *(const frag8*)(&Kms[nf * 16 + l15][32 + (lg << 3)]);
      sacc[nf] = __builtin_amdgcn_mfma_f32_16x16x32_bf16(qh0, kh0, sacc[nf], 0, 0, 0);
      sacc[nf] = __builtin_amdgcn_mfma_f32_16x16x32_bf16(qh1, kh1, sacc[nf], 0, 0, 0);
      sacc[nf] = __builtin_amdgcn_mfma_f32_16x16x32_bf16(qh0, km0, sacc[nf], 0, 0, 0);
      sacc[nf] = __builtin_amdgcn_mfma_f32_16x16x32_bf16(qh1, km1, sacc[nf], 0, 0, 0);
      sacc[nf] = __builtin_amdgcn_mfma_f32_16x16x32_bf16(qm0, kh0, sacc[nf], 0, 0, 0);
      sacc[nf] = __builtin_amdgcn_mfma_f32_16x16x32_bf16(qm1, kh1, sacc[nf], 0, 0, 0);
    }
#pragma unroll
    for (int r = 0; r < 4; ++r) {
      float tm = fmaxf(fmaxf(sacc[0][r], sacc[1][r]), fmaxf(sacc[2][r], sacc[3][r]));
      tm = fmaxf(tm, __shfl_xor(tm, 1));
      tm = fmaxf(tm, __shfl_xor(tm, 2));
      tm = fmaxf(tm, __shfl_xor(tm, 4));
      tm = fmaxf(tm, __shfl_xor(tm, 8));
      float nm = fmaxf(mrun[r], tm);
      float al = expf(mrun[r] - nm);
      float p0 = expf(sacc[0][r] - nm);
      float p1 = expf(sacc[1][r] - nm);
      float p2 = expf(sacc[2][r] - nm);
      float p3 = expf(sacc[3][r] - nm);
      float rs = p0 + p1 + p2 + p3;
      rs += __shfl_xor(rs, 1);
      rs += __shfl_xor(rs, 2);
      rs += __shfl_xor(rs, 4);
      rs += __shfl_xor(rs, 8);
      srun[r] = srun[r] * al + rs;
      mrun[r] = nm;
#pragma unroll
      for (int hf = 0; hf < 4; ++hf) oacc[hf][r] *= al;
      int prow = w * 16 + lg * 4 + r;
      ushort_t ph, pm;
      splitf(p0, ph, pm); Phs[prow][0 * 16 + l15] = ph; Pms[prow][0 * 16 + l15] = pm;
      splitf(p1, ph, pm); Phs[prow][1 * 16 + l15] = ph; Pms[prow][1 * 16 + l15] = pm;
      splitf(p2, ph, pm); Phs[prow][2 * 16 + l15] = ph; Pms[prow][2 * 16 + l15] = pm;
      splitf(p3, ph, pm); Phs[prow][3 * 16 + l15] = ph; Pms[prow][3 * 16 + l15] = pm;
    }
    __syncthreads();
#pragma unroll
    for (int kg = 0; kg < 2; ++kg) {
      frag8 pf = *(const frag8*)(&Phs[w * 16 + l15][kg * 32 + (lg << 3)]);
      frag8 pf2 = *(const frag8*)(&Pms[w * 16 + l15][kg * 32 + (lg << 3)]);
#pragma unroll
      for (int hf = 0; hf < 4; ++hf) {
        frag8 vf = *(const frag8*)(&Vhs[hf * 16 + l15][kg * 32 + (lg << 3)]);
        frag8 vf2 = *(const frag8*)(&Vms[hf * 16 + l15][kg * 32 + (lg << 3)]);
        oacc[hf] = __builtin_amdgcn_mfma_f32_16x16x32_bf16(pf, vf, oacc[hf], 0, 0, 0);
        oacc[hf] = __builtin_amdgcn_mfma_f32_16x16x32_bf16(pf, vf2, oacc[hf], 0, 0, 0);
        oacc[hf] = __builtin_amdgcn_mfma_f32_16x16x32_bf16(pf2, vf, oacc[hf], 0, 0, 0);
      }
    }
  }
#pragma unroll
  for (int hf = 0; hf < 4; ++hf)
#pragma unroll
    for (int r = 0; r < 4; ++r) {
      float val = oacc[hf][r] / srun[r];
      size_t off = base + (size_t)(qt * 64 + w * 16 + lg * 4 + r) * 1024 + hf * 16 + l15;
      ushort_t h, m;
      splitf(val, h, m);
      oh[off] = h;
      om[off] = m;
    }
}

// ---------------- 4x4 pooling + mask ----------------
__global__ __launch_bounds__(256) void k_pool(const float* __restrict__ x,
                                              const int* __restrict__ pos,
                                              float* __restrict__ out,
                                              float* __restrict__ maskout) {
  __shared__ int smax[4];
  __shared__ int kidx_s[1024];
  const int blk = blockIdx.x;
  const int b = blk >> 6, oidx = blk & 63;
  const int tid = threadIdx.x;
  int mx = 0;
  for (int l = tid; l < 1024; l += 256) {
    int p0 = pos[((size_t)b * 1024 + l) * 2];
    mx = max(mx, p0 > 0 ? p0 : 0);
  }
  for (int m = 1; m < 64; m <<= 1) mx = max(mx, __shfl_xor(mx, m));
  if ((tid & 63) == 0) smax[tid >> 6] = mx;
  __syncthreads();
  int maxx = max(max(smax[0], smax[1]), max(smax[2], smax[3])) + 1;
  int mk = maxx >> 2;
  for (int l = tid; l < 1024; l += 256) {
    int p0 = pos[((size_t)b * 1024 + l) * 2];
    int p1 = pos[((size_t)b * 1024 + l) * 2 + 1];
    int c0 = p0 > 0 ? p0 : 0, c1 = p1 > 0 ? p1 : 0;
    int pad = (p0 == -1 && p1 == -1) ? 1 : 0;
    kidx_s[l] = ((c0 >> 2) + mk * (c1 >> 2)) | (pad << 16);
  }
  __syncthreads();
  float ax = 0.f, ay = 0.f, az = 0.f, aw = 0.f;
  int cnt = 0;
  for (int l = 0; l < 1024; ++l) {
    int ki = kidx_s[l];
    if ((ki & 0xffff) == oidx) {
      cnt++;
      if (!(ki >> 16)) {
        float4 xv = ((const float4*)(x + ((size_t)b * 1024 + l) * 1024))[tid];
        ax += xv.x; ay += xv.y; az += xv.z; aw += xv.w;
      }
    }
  }
  float4 res;
  res.x = ax * 2.0f; res.y = ay * 2.0f; res.z = az * 2.0f; res.w = aw * 2.0f;
  ((float4*)(out + ((size_t)b * 64 + oidx) * 1024))[tid] = res;
  if (tid == 0) maskout[b * 64 + oidx] = (cnt > 0) ? 1.0f : 0.0f;
}

// ---------------- host launch ----------------
extern "C" void kernel_launch(void* const* d_in, const int* in_sizes, int n_in,
                              void* d_out, int out_size, void* d_ws, size_t ws_size,
                              hipStream_t stream) {
  const float* pix = (const float*)d_in[0];
  const int* pos = (const int*)d_in[1];
  const float* Win = (const float*)d_in[2];
  const float* ptab = (const float*)d_in[3];
  const float* Wq = (const float*)d_in[4];
  const float* Wk = (const float*)d_in[5];
  const float* Wv = (const float*)d_in[6];
  const float* Wo = (const float*)d_in[7];
  const float* qn = (const float*)d_in[8];
  const float* kn = (const float*)d_in[9];
  const float* pre_attn = (const float*)d_in[10];
  const float* post_attn = (const float*)d_in[11];
  const float* pre_ffw = (const float*)d_in[12];
  const float* post_ffw = (const float*)d_in[13];
  const float* Wg = (const float*)d_in[14];
  const float* Wu = (const float*)d_in[15];
  const float* Wd = (const float*)d_in[16];

  char* w = (char*)d_ws;
  float* x = (float*)w;        w += 16777216;
  float* tmp = (float*)w;      w += 16777216;
  ushort_t* hh = (ushort_t*)w; w += 8388608;
  ushort_t* hm = (ushort_t*)w; w += 8388608;
  char* regB = w;  // 128 MiB overlapped region
  ushort_t* qh_ = (ushort_t*)(regB + 0);
  ushort_t* qm_ = (ushort_t*)(regB + 8388608);
  ushort_t* kh_ = (ushort_t*)(regB + 16777216);
  ushort_t* km_ = (ushort_t*)(regB + 25165824);
  ushort_t* vh_ = (ushort_t*)(regB + 33554432);
  ushort_t* vm_ = (ushort_t*)(regB + 41943040);
  ushort_t* aoh = (ushort_t*)(regB + 50331648);
  ushort_t* aom = (ushort_t*)(regB + 58720256);
  ushort_t* wat_h = (ushort_t*)(regB + 67108864);
  ushort_t* wat_m = (ushort_t*)(regB + 75497472);
  float* t2o = (float*)(regB + 0);
  ushort_t* mh = (ushort_t*)(regB + 0);
  ushort_t* mm = (ushort_t*)(regB + 33554432);
  ushort_t* wgu_h = (ushort_t*)(regB + 67108864);
  ushort_t* wgu_m = (ushort_t*)(regB + 83886080);
  ushort_t* wd_h = (ushort_t*)(regB + 100663296);
  ushort_t* wd_m = (ushort_t*)(regB + 109051904);
  float* t2d = (float*)(regB + 67108864);
  ushort_t* pixh = (ushort_t*)(regB + 0);
  ushort_t* pixm = (ushort_t*)(regB + 6291456);
  ushort_t* win_h = (ushort_t*)(regB + 67108864);
  ushort_t* win_m = (ushort_t*)(regB + 71303168);

  dim3 blk(256);
  k_splitpix<<<3072, blk, 0, stream>>>(pix, pixh, pixm, 786432);
  k_posemb<<<4096, blk, 0, stream>>>(pos, ptab, x);
  k_wsplit4<<<dim3(16, 12, 1), blk, 0, stream>>>(Win, Win, Win, Win, win_h, win_m, 768, 1024);
  k_gemm_s<EPI_ADDF32><<<256, blk, 0, stream>>>(pixh, pixm, win_h, win_m, x, nullptr,
                                                768, 1024, 24);
  k_rmsnorm_s<<<4096, blk, 0, stream>>>(x, pre_attn, hh, hm);

  for (int i = 0; i < 6; ++i) {
    const float* wq = Wq + (size_t)i * 1048576;
    const float* wk = Wk + (size_t)i * 1048576;
    const float* wv = Wv + (size_t)i * 1048576;
    const float* wo = Wo + (size_t)i * 1048576;
    const float* wg = Wg + (size_t)i * 4194304;
    const float* wu = Wu + (size_t)i * 4194304;
    const float* wd = Wd + (size_t)i * 4194304;

    k_wsplit4<<<dim3(16, 16, 4), blk, 0, stream>>>(wq, wk, wv, wo, wat_h, wat_m, 1024, 1024);
    k_qkv<<<768, blk, 0, stream>>>(hh, hm, wat_h, wat_m, qn + i * 64, kn + i * 64, pos,
                                   qh_, qm_, kh_, km_, vh_, vm_);
    k_attn_s<<<1024, blk, 0, stream>>>(qh_, qm_, kh_, km_, vh_, vm_, aoh, aom);
    k_gemm_s<EPI_F32><<<512, blk, 0, stream>>>(aoh, aom, wat_h + 3145728, wat_m + 3145728,
                                               tmp, t2o, 1024, 1024, 16);
    // fused: x += rms(tmp+t2o)*post_attn ; hh/hm = split(rms(x)*pre_ffw)
    k_addrms_ns<<<4096, blk, 0, stream>>>(x, tmp, t2o, post_attn + i * 1024,
                                          pre_ffw + i * 1024, hh, hm);

    k_wsplit4<<<dim3(64, 16, 2), blk, 0, stream>>>(wg, wu, wg, wu, wgu_h, wgu_m, 1024, 4096);
    k_wsplit4<<<dim3(16, 64, 1), blk, 0, stream>>>(wd, wd, wd, wd, wd_h, wd_m, 4096, 1024);
    k_ffw_up<<<1024, blk, 0, stream>>>(hh, hm, wgu_h, wgu_m, wgu_h + 4194304, wgu_m + 4194304,
                                       mh, mm);
    k_gemm_s<EPI_F32><<<512, blk, 0, stream>>>(mh, mm, wd_h, wd_m, tmp, t2d, 4096, 1024, 64);
    if (i < 5) {
      // fused: x += rms(tmp+t2d)*post_ffw ; hh/hm = split(rms(x)*pre_attn[i+1])
      k_addrms_ns<<<4096, blk, 0, stream>>>(x, tmp, t2d, post_ffw + i * 1024,
                                            pre_attn + (i + 1) * 1024, hh, hm);
    } else {
      k_addrms32<<<4096, blk, 0, stream>>>(x, tmp, t2d, post_ffw + i * 1024);
    }
  }

  k_pool<<<256, blk, 0, stream>>>(x, pos, (float*)d_out, (float*)d_out + 262144);
}